// Round 10
// baseline (451.403 us; speedup 1.0000x reference)
//
#include <hip/hip_runtime.h>

#define NN 50000
#define NE 800000
#define D 256
#define DOUT 128

// bucket sort params: 196 buckets of 256 nodes; 98 blocks of 8192 edges
#define NBUCK 196
#define EPB 8192
#define NBLK 98
#define NSCAN (NBUCK * NBLK)  // 19208

typedef __attribute__((ext_vector_type(8))) short bf16x8;
typedef __attribute__((ext_vector_type(8))) ushort u16x8;
typedef __attribute__((ext_vector_type(4))) float f32x4;
typedef __attribute__((ext_vector_type(2))) float f32x2;

__device__ __forceinline__ ushort f2b(float f) {
    union { float f; unsigned u; } v; v.f = f;
    unsigned u = v.u + 0x7fffu + ((v.u >> 16) & 1u);
    return (ushort)(u >> 16);
}
__device__ __forceinline__ unsigned char f2fp8(float f) {
    return (unsigned char)(__builtin_amdgcn_cvt_pk_fp8_f32(f, 0.f, 0, 0) & 0xff);
}
// two f32 -> packed 2x bf16 in one instr (no builtin on gfx950)
__device__ __forceinline__ unsigned cvt2bf(float lo, float hi) {
    unsigned r;
    asm volatile("v_cvt_pk_bf16_f32 %0, %1, %2" : "=v"(r) : "v"(lo), "v"(hi));
    return r;
}

// ---------------- bucketed CSR build ----------------
__global__ __launch_bounds__(256) void bcount_kernel(const int* __restrict__ dst,
                                                     int* __restrict__ gcnt, int E) {
    __shared__ int hist[NBUCK];
    const int b = blockIdx.x;
    for (int i = threadIdx.x; i < NBUCK; i += 256) hist[i] = 0;
    __syncthreads();
    const int e0 = b * EPB;
    const int e1 = min(e0 + EPB, E);
    for (int e = e0 + threadIdx.x; e < e1; e += 256)
        atomicAdd(&hist[dst[e] >> 8], 1);
    __syncthreads();
    for (int q = threadIdx.x; q < NBUCK; q += 256)
        gcnt[q * NBLK + b] = hist[q];
}

// 3-phase exclusive scan (generic n)
__global__ __launch_bounds__(256) void scanA_kernel(const int* __restrict__ deg,
                                                    int* __restrict__ blk, int n) {
    __shared__ int red[4];
    const int i = blockIdx.x * 256 + threadIdx.x;
    int v = (i < n) ? deg[i] : 0;
    #pragma unroll
    for (int off = 32; off > 0; off >>= 1) v += __shfl_xor(v, off);
    if ((threadIdx.x & 63) == 0) red[threadIdx.x >> 6] = v;
    __syncthreads();
    if (threadIdx.x == 0) blk[blockIdx.x] = red[0] + red[1] + red[2] + red[3];
}

__global__ __launch_bounds__(256) void scanB_kernel(int* __restrict__ blk, int nb) {
    __shared__ int s[256];
    const int t = threadIdx.x;
    const int v = (t < nb) ? blk[t] : 0;
    s[t] = v;
    __syncthreads();
    for (int off = 1; off < 256; off <<= 1) {
        int u = (t >= off) ? s[t - off] : 0;
        __syncthreads();
        s[t] += u;
        __syncthreads();
    }
    if (t < nb) blk[t] = s[t] - v;  // exclusive
}

__global__ __launch_bounds__(256) void scanC_kernel(const int* __restrict__ deg,
                                                    const int* __restrict__ blk,
                                                    int* __restrict__ out, int n) {
    __shared__ int s[256];
    const int t = threadIdx.x;
    const int i = blockIdx.x * 256 + t;
    const int v = (i < n) ? deg[i] : 0;
    s[t] = v;
    __syncthreads();
    for (int off = 1; off < 256; off <<= 1) {
        int u = (t >= off) ? s[t - off] : 0;
        __syncthreads();
        s[t] += u;
        __syncthreads();
    }
    if (i <= n) out[i] = blk[blockIdx.x] + s[t] - v;
}

__global__ __launch_bounds__(256) void bscatter_kernel(const int* __restrict__ src,
                                                       const int* __restrict__ dst,
                                                       const int* __restrict__ roff,
                                                       unsigned* __restrict__ ebuf, int E) {
    __shared__ int cur[NBUCK];
    const int b = blockIdx.x;
    for (int q = threadIdx.x; q < NBUCK; q += 256) cur[q] = roff[q * NBLK + b];
    __syncthreads();
    const int e0 = b * EPB;
    const int e1 = min(e0 + EPB, E);
    for (int e = e0 + threadIdx.x; e < e1; e += 256) {
        const int d = dst[e];
        const int pos = atomicAdd(&cur[d >> 8], 1);
        ebuf[pos] = ((unsigned)(d & 255) << 16) | (unsigned)src[e];
    }
}

// one block per bucket: local CSR (contiguous csr region per bucket -> XCD-local writes)
__global__ __launch_bounds__(256) void bcsr_kernel(const unsigned* __restrict__ ebuf,
                                                   const int* __restrict__ roff,
                                                   int* __restrict__ csr_src,
                                                   int* __restrict__ row_ptr,
                                                   float* __restrict__ invd) {
    __shared__ int degs[256];
    __shared__ int scn[256];
    __shared__ int cur[256];
    const int q = blockIdx.x;
    const int t = threadIdx.x;
    const int start = roff[q * NBLK];
    const int end = (q == NBUCK - 1) ? NE : roff[(q + 1) * NBLK];
    degs[t] = 0;
    __syncthreads();
    for (int e = start + t; e < end; e += 256)
        atomicAdd(&degs[ebuf[e] >> 16], 1);
    __syncthreads();
    const int v = degs[t];
    scn[t] = v;
    __syncthreads();
    for (int off = 1; off < 256; off <<= 1) {
        int u = (t >= off) ? scn[t - off] : 0;
        __syncthreads();
        scn[t] += u;
        __syncthreads();
    }
    const int excl = scn[t] - v;
    cur[t] = start + excl;
    __syncthreads();
    for (int e = start + t; e < end; e += 256) {
        const unsigned p = ebuf[e];
        const int pos = atomicAdd(&cur[p >> 16], 1);
        csr_src[pos] = (int)(p & 0xffffu);
    }
    const int node = q * 256 + t;
    if (node < NN) {
        row_ptr[node] = start + excl;
        invd[node] = 1.0f / fmaxf((float)v, 1.0f);
    }
    if (q == NBUCK - 1 && t == 0) row_ptr[NN] = NE;
}

// ---------------- converts ----------------
__global__ void cvt_x_kernel(const float* __restrict__ in, ushort* __restrict__ outb,
                             unsigned* __restrict__ out8, int n4) {
    int i = blockIdx.x * blockDim.x + threadIdx.x;
    if (i >= n4) return;
    const float4 v = *reinterpret_cast<const float4*>(in + (size_t)i * 4);
    ushort4 o;
    o.x = f2b(v.x); o.y = f2b(v.y); o.z = f2b(v.z); o.w = f2b(v.w);
    *reinterpret_cast<ushort4*>(outb + (size_t)i * 4) = o;
    unsigned p = __builtin_amdgcn_cvt_pk_fp8_f32(v.x, v.y, 0, 0);
    p = __builtin_amdgcn_cvt_pk_fp8_f32(v.z, v.w, p, 1);
    out8[i] = p;
}

// in: [nmat][256][ncol] f32  ->  out: [nmat][ncol][256] bf16 (transposed per matrix)
__global__ void cvt_wt_kernel(const float* __restrict__ in, ushort* __restrict__ out,
                              int nmat, int ncol) {
    int idx = blockIdx.x * blockDim.x + threadIdx.x;
    int total = nmat * 256 * ncol;
    if (idx >= total) return;
    int k = idx & 255;
    int t = idx >> 8;
    int n = t % ncol;
    int m = t / ncol;
    out[idx] = f2b(in[(size_t)m * 256 * ncol + (size_t)k * ncol + n]);
}

// ---------------- column-sliced gather-mean over fp8 rows -> fp8 agg ----------------
// grid (nodeblocks, 4 slices). Slice s touches only bytes s*64..s*64+63 of each row
// -> 3.2 MB active table slice fits one XCD L2. One wave per (node, slice);
// 4 groups of 16 lanes walk neighbors i+g / i+4+g; lane reads 4B (4 fp8 cols).
__global__ __launch_bounds__(256) void gather_kernel(const unsigned char* __restrict__ h8,
                                                     const int* __restrict__ csr_src,
                                                     const int* __restrict__ row_ptr,
                                                     const float* __restrict__ invd,
                                                     unsigned char* __restrict__ agg8, int n) {
    const int node = blockIdx.x * 4 + (threadIdx.x >> 6);
    const int sl = blockIdx.y;
    const int lane = threadIdx.x & 63;
    if (node >= n) return;
    const int beg = row_ptr[node];
    const int end = row_ptr[node + 1];
    const int g = lane >> 4;
    const int l16 = lane & 15;
    const unsigned char* base = h8 + sl * 64 + l16 * 4;

    f32x2 a0 = {0.f, 0.f}, a1 = {0.f, 0.f};

    int i = beg;
    for (; i + 7 < end; i += 8) {
        const int s0 = csr_src[i + g];
        const int s1 = csr_src[i + 4 + g];
        const unsigned w0 = *reinterpret_cast<const unsigned*>(base + (size_t)s0 * D);
        const unsigned w1 = *reinterpret_cast<const unsigned*>(base + (size_t)s1 * D);
        a0 += __builtin_amdgcn_cvt_pk_f32_fp8(w0, 0);
        a1 += __builtin_amdgcn_cvt_pk_f32_fp8(w0, 1);
        a0 += __builtin_amdgcn_cvt_pk_f32_fp8(w1, 0);
        a1 += __builtin_amdgcn_cvt_pk_f32_fp8(w1, 1);
    }
    #pragma unroll
    for (int t = 0; t < 2; ++t) {
        const int idx = i + 4 * t + g;
        if (idx < end) {
            const int s = csr_src[idx];
            const unsigned w = *reinterpret_cast<const unsigned*>(base + (size_t)s * D);
            a0 += __builtin_amdgcn_cvt_pk_f32_fp8(w, 0);
            a1 += __builtin_amdgcn_cvt_pk_f32_fp8(w, 1);
        }
    }
    float a[4] = {a0.x, a0.y, a1.x, a1.y};
    #pragma unroll
    for (int j = 0; j < 4; ++j) {
        a[j] += __shfl_xor(a[j], 16);
        a[j] += __shfl_xor(a[j], 32);
    }
    if (g == 0) {
        const float sc = invd[node];
        unsigned r = __builtin_amdgcn_cvt_pk_fp8_f32(a[0] * sc, a[1] * sc, 0, 0);
        r = __builtin_amdgcn_cvt_pk_fp8_f32(a[2] * sc, a[3] * sc, r, 1);
        *reinterpret_cast<unsigned*>(agg8 + (size_t)node * D + sl * 64 + l16 * 4) = r;
    }
}

// ---------------- bf16 MFMA GEMM, 128 rows x 256 cols per block, 512 threads ----------------
// A0F8: A0 operand is fp8 (converted to bf16 in staging; LDS/MFMA unchanged).
template <bool DUAL, bool RELU, bool OUTBF, bool OUT8, bool A0F8>
__global__ __launch_bounds__(512) void mgemm256_kernel(
    const unsigned char* __restrict__ A08, const ushort* __restrict__ A0b,
    const ushort* __restrict__ A1,
    const ushort* __restrict__ B0T, const ushort* __restrict__ B1T,
    const float* __restrict__ bias, void* __restrict__ out,
    unsigned char* __restrict__ out8, int N)
{
    __shared__ ushort As[128][40];
    __shared__ ushort Bs[256][40];

    const int tid = threadIdx.x;
    const int wave = tid >> 6;
    const int lane = tid & 63;
    const int wm = wave >> 2;
    const int wn = wave & 3;
    const int l15 = lane & 15;
    const int l4 = lane >> 4;
    const int r0 = blockIdx.x * 128;

    const f32x4 zero = {0.f, 0.f, 0.f, 0.f};
    f32x4 acc[4][4];
    #pragma unroll
    for (int i = 0; i < 4; ++i)
        #pragma unroll
        for (int j = 0; j < 4; ++j) acc[i][j] = zero;

    const int arr = tid >> 2;
    const int ach = (tid & 3) * 8;
    const int agrow = min(r0 + arr, N - 1);

    const int NT = DUAL ? 16 : 8;
    for (int kt = 0; kt < NT; ++kt) {
        const bool second = DUAL && (kt >= 8);
        const ushort* BT = second ? B1T : B0T;
        const int kb = (second ? (kt - 8) : kt) * 32;

        if (!second && A0F8) {
            const uint2 q = *reinterpret_cast<const uint2*>(A08 + (size_t)agrow * 256 + kb + ach);
            const f32x2 f0 = __builtin_amdgcn_cvt_pk_f32_fp8(q.x, 0);
            const f32x2 f1 = __builtin_amdgcn_cvt_pk_f32_fp8(q.x, 1);
            const f32x2 f2 = __builtin_amdgcn_cvt_pk_f32_fp8(q.y, 0);
            const f32x2 f3 = __builtin_amdgcn_cvt_pk_f32_fp8(q.y, 1);
            uint4 o;
            o.x = cvt2bf(f0.x, f0.y);
            o.y = cvt2bf(f1.x, f1.y);
            o.z = cvt2bf(f2.x, f2.y);
            o.w = cvt2bf(f3.x, f3.y);
            *reinterpret_cast<uint4*>(&As[arr][ach]) = o;
        } else {
            const ushort* A = second ? A1 : A0b;
            *reinterpret_cast<float4*>(&As[arr][ach]) =
                *reinterpret_cast<const float4*>(A + (size_t)agrow * 256 + kb + ach);
        }
        #pragma unroll
        for (int it = 0; it < 2; ++it) {
            const int idx = it * 512 + tid;
            const int br = idx >> 2;
            const int ch = (idx & 3) * 8;
            *reinterpret_cast<float4*>(&Bs[br][ch]) =
                *reinterpret_cast<const float4*>(BT + (size_t)br * 256 + kb + ch);
        }
        __syncthreads();

        bf16x8 af[4], bfr[4];
        #pragma unroll
        for (int i = 0; i < 4; ++i)
            af[i] = *reinterpret_cast<const bf16x8*>(&As[wm * 64 + 16 * i + l15][l4 * 8]);
        #pragma unroll
        for (int j = 0; j < 4; ++j)
            bfr[j] = *reinterpret_cast<const bf16x8*>(&Bs[wn * 64 + 16 * j + l15][l4 * 8]);
        #pragma unroll
        for (int i = 0; i < 4; ++i)
            #pragma unroll
            for (int j = 0; j < 4; ++j)
                acc[i][j] = __builtin_amdgcn_mfma_f32_16x16x32_bf16(af[i], bfr[j], acc[i][j], 0, 0, 0);
        __syncthreads();
    }

    const int rbase = r0 + wm * 64;
    const int cbase = wn * 64;
    #pragma unroll
    for (int i = 0; i < 4; ++i) {
        #pragma unroll
        for (int r = 0; r < 4; ++r) {
            const int row = rbase + 16 * i + l4 * 4 + r;
            if (row < N) {
                #pragma unroll
                for (int j = 0; j < 4; ++j) {
                    const int col = cbase + 16 * j + l15;
                    float v = acc[i][j][r] + bias[col];
                    if (RELU) v = fmaxf(v, 0.f);
                    if (OUTBF)
                        ((ushort*)out)[(size_t)row * 256 + col] = f2b(v);
                    else
                        ((float*)out)[(size_t)row * 256 + col] = v;
                    if (OUT8)
                        out8[(size_t)row * 256 + col] = f2fp8(v);
                }
            }
        }
    }
}

// ---------------- final GEMM (128 cols) with fused log-softmax ----------------
__global__ __launch_bounds__(256) void mgemm128sm_kernel(
    const ushort* __restrict__ A0, const ushort* __restrict__ B0T,
    const float* __restrict__ bias, float* __restrict__ out, int N)
{
    __shared__ ushort As[128][40];
    __shared__ ushort Bs[128][40];
    __shared__ float msh[2][128];
    __shared__ float ssh[2][128];

    const int tid = threadIdx.x;
    const int wave = tid >> 6;
    const int lane = tid & 63;
    const int wm = wave >> 1;
    const int wn = wave & 1;
    const int l15 = lane & 15;
    const int l4 = lane >> 4;
    const int r0 = blockIdx.x * 128;

    const f32x4 zero = {0.f, 0.f, 0.f, 0.f};
    f32x4 acc[4][4];
    #pragma unroll
    for (int i = 0; i < 4; ++i)
        #pragma unroll
        for (int j = 0; j < 4; ++j) acc[i][j] = zero;

    for (int kt = 0; kt < 8; ++kt) {
        const int kb = kt * 32;
        #pragma unroll
        for (int it = 0; it < 2; ++it) {
            const int idx = it * 256 + tid;
            const int rr = idx >> 2;
            const int ch = (idx & 3) * 8;
            const int grow = min(r0 + rr, N - 1);
            *reinterpret_cast<float4*>(&As[rr][ch]) =
                *reinterpret_cast<const float4*>(A0 + (size_t)grow * 256 + kb + ch);
            *reinterpret_cast<float4*>(&Bs[rr][ch]) =
                *reinterpret_cast<const float4*>(B0T + (size_t)rr * 256 + kb + ch);
        }
        __syncthreads();

        bf16x8 af[4], bfr[4];
        #pragma unroll
        for (int i = 0; i < 4; ++i)
            af[i] = *reinterpret_cast<const bf16x8*>(&As[wm * 64 + 16 * i + l15][l4 * 8]);
        #pragma unroll
        for (int j = 0; j < 4; ++j)
            bfr[j] = *reinterpret_cast<const bf16x8*>(&Bs[wn * 64 + 16 * j + l15][l4 * 8]);
        #pragma unroll
        for (int i = 0; i < 4; ++i)
            #pragma unroll
            for (int j = 0; j < 4; ++j)
                acc[i][j] = __builtin_amdgcn_mfma_f32_16x16x32_bf16(af[i], bfr[j], acc[i][j], 0, 0, 0);
        __syncthreads();
    }

    const int cbase = wn * 64;
    float bb[4];
    #pragma unroll
    for (int j = 0; j < 4; ++j) bb[j] = bias[cbase + 16 * j + l15];

    #pragma unroll
    for (int i = 0; i < 4; ++i) {
        #pragma unroll
        for (int r = 0; r < 4; ++r) {
            float v0 = acc[i][0][r] + bb[0];
            float v1 = acc[i][1][r] + bb[1];
            float v2 = acc[i][2][r] + bb[2];
            float v3 = acc[i][3][r] + bb[3];
            float m = fmaxf(fmaxf(v0, v1), fmaxf(v2, v3));
            #pragma unroll
            for (int off = 8; off > 0; off >>= 1) m = fmaxf(m, __shfl_xor(m, off));
            float s = expf(v0 - m) + expf(v1 - m) + expf(v2 - m) + expf(v3 - m);
            #pragma unroll
            for (int off = 8; off > 0; off >>= 1) s += __shfl_xor(s, off);
            if (l15 == 0) {
                const int lr = wm * 64 + 16 * i + l4 * 4 + r;
                msh[wn][lr] = m;
                ssh[wn][lr] = s;
            }
        }
    }
    __syncthreads();

    #pragma unroll
    for (int i = 0; i < 4; ++i) {
        #pragma unroll
        for (int r = 0; r < 4; ++r) {
            const int lr = wm * 64 + 16 * i + l4 * 4 + r;
            const float m0 = msh[0][lr], m1 = msh[1][lr];
            const float s0 = ssh[0][lr], s1 = ssh[1][lr];
            const float M = fmaxf(m0, m1);
            const float ls = M + logf(s0 * expf(m0 - M) + s1 * expf(m1 - M));
            const int row = r0 + lr;
            if (row < N) {
                #pragma unroll
                for (int j = 0; j < 4; ++j)
                    out[(size_t)row * DOUT + cbase + 16 * j + l15] = acc[i][j][r] + bb[j] - ls;
            }
        }
    }
}

extern "C" void kernel_launch(void* const* d_in, const int* in_sizes, int n_in,
                              void* d_out, int out_size, void* d_ws, size_t ws_size,
                              hipStream_t stream) {
    const float* x  = (const float*)d_in[0];
    const int* ei   = (const int*)d_in[1];
    const float* wl = (const float*)d_in[2];
    const float* bl = (const float*)d_in[3];
    const float* wr = (const float*)d_in[4];
    const float* w1 = (const float*)d_in[5];
    const float* b1 = (const float*)d_in[6];
    const float* w2 = (const float*)d_in[7];
    const float* b2 = (const float*)d_in[8];
    const int* src = ei;
    const int* dst = ei + NE;

    // ---- workspace layout ----
    ushort* hx   = (ushort*)d_ws;                 // NN*D bf16
    ushort* hA   = hx + (size_t)NN * D;
    ushort* hB   = hA + (size_t)NN * D;
    ushort* wlT  = hB + (size_t)NN * D;           // 3*256*256
    ushort* wrT  = wlT + 3 * 256 * 256;
    ushort* w1T  = wrT + 3 * 256 * 256;
    ushort* w2T  = w1T + 256 * 256;               // 128*256
    unsigned char* h8x = (unsigned char*)(w2T + 128 * 256);  // NN*D fp8
    unsigned char* h8A = h8x + (size_t)NN * D;
    unsigned char* h8B = h8A + (size_t)NN * D;
    unsigned char* agg8 = h8B + (size_t)NN * D;   // NN*D fp8
    float* invd  = (float*)(agg8 + (size_t)NN * D);  // NN
    int* row_ptr = (int*)(invd + NN);               // NN+1
    int* csr_src = row_ptr + NN + 1;                // NE
    unsigned* ebuf = (unsigned*)(csr_src + NE);     // NE
    int* gcnt    = (int*)(ebuf + NE);               // NSCAN
    int* roff    = gcnt + NSCAN;                    // NSCAN+1
    int* blk     = roff + NSCAN + 1;                // 256
    float* outf  = (float*)d_out;

    // ---- CSR build (counting sort, XCD-local writes) ----
    const int NSB = (NSCAN + 256) / 256;  // 77
    bcount_kernel<<<NBLK, 256, 0, stream>>>(dst, gcnt, NE);
    scanA_kernel<<<NSB, 256, 0, stream>>>(gcnt, blk, NSCAN);
    scanB_kernel<<<1, 256, 0, stream>>>(blk, NSB);
    scanC_kernel<<<NSB, 256, 0, stream>>>(gcnt, blk, roff, NSCAN);
    bscatter_kernel<<<NBLK, 256, 0, stream>>>(src, dst, roff, ebuf, NE);
    bcsr_kernel<<<NBUCK, 256, 0, stream>>>(ebuf, roff, csr_src, row_ptr, invd);

    // ---- converts ----
    cvt_x_kernel<<<(NN * D / 4 + 255) / 256, 256, 0, stream>>>(x, hx, (unsigned*)h8x, NN * D / 4);
    cvt_wt_kernel<<<(3 * 256 * 256 + 255) / 256, 256, 0, stream>>>(wl, wlT, 3, 256);
    cvt_wt_kernel<<<(3 * 256 * 256 + 255) / 256, 256, 0, stream>>>(wr, wrT, 3, 256);
    cvt_wt_kernel<<<(256 * 256 + 255) / 256, 256, 0, stream>>>(w1, w1T, 1, 256);
    cvt_wt_kernel<<<(128 * 256 + 255) / 256, 256, 0, stream>>>(w2, w2T, 1, 128);

    const int gpan = (NN + 127) / 128;
    const dim3 gg((NN + 3) / 4, 4);   // x = node blocks, y = column slice

    // layer 0: gather(h8x)->agg8 ; DUAL(agg8 fp8, hx) -> hA (+h8A)
    gather_kernel<<<gg, 256, 0, stream>>>(h8x, csr_src, row_ptr, invd, agg8, NN);
    mgemm256_kernel<true, true, true, true, true><<<gpan, 512, 0, stream>>>(
        agg8, nullptr, hx, wlT, wrT, bl, hA, h8A, NN);
    // layer 1
    gather_kernel<<<gg, 256, 0, stream>>>(h8A, csr_src, row_ptr, invd, agg8, NN);
    mgemm256_kernel<true, true, true, true, true><<<gpan, 512, 0, stream>>>(
        agg8, nullptr, hA, wlT + 256 * 256, wrT + 256 * 256, bl + 256, hB, h8B, NN);
    // layer 2 (no fp8 output needed)
    gather_kernel<<<gg, 256, 0, stream>>>(h8B, csr_src, row_ptr, invd, agg8, NN);
    mgemm256_kernel<true, true, true, false, true><<<gpan, 512, 0, stream>>>(
        agg8, nullptr, hB, wlT + 2 * 256 * 256, wrT + 2 * 256 * 256, bl + 2 * 256, hA, nullptr, NN);
    // post-mp
    mgemm256_kernel<false, false, true, false, false><<<gpan, 512, 0, stream>>>(
        nullptr, hA, nullptr, w1T, nullptr, b1, hB, nullptr, NN);
    mgemm128sm_kernel<<<gpan, 256, 0, stream>>>(hB, w2T, b2, outf, NN);
}

// Round 11
// 331.523 us; speedup vs baseline: 1.3616x; 1.3616x over previous
//
#include <hip/hip_runtime.h>

#define NN 50000
#define NE 800000
#define D 256
#define DOUT 128

// bucket sort params: 196 buckets of 256 nodes; 98 blocks of 8192 edges
#define NBUCK 196
#define EPB 8192
#define NBLK 98
#define NSCAN (NBUCK * NBLK)  // 19208

typedef __attribute__((ext_vector_type(8))) short bf16x8;
typedef __attribute__((ext_vector_type(8))) ushort u16x8;
typedef __attribute__((ext_vector_type(4))) float f32x4;
typedef __attribute__((ext_vector_type(2))) float f32x2;

__device__ __forceinline__ ushort f2b(float f) {
    union { float f; unsigned u; } v; v.f = f;
    unsigned u = v.u + 0x7fffu + ((v.u >> 16) & 1u);
    return (ushort)(u >> 16);
}
__device__ __forceinline__ unsigned char f2fp8(float f) {
    return (unsigned char)(__builtin_amdgcn_cvt_pk_fp8_f32(f, 0.f, 0, 0) & 0xff);
}
// two f32 -> packed 2x bf16 in one instr (no builtin on gfx950)
__device__ __forceinline__ unsigned cvt2bf(float lo, float hi) {
    unsigned r;
    asm volatile("v_cvt_pk_bf16_f32 %0, %1, %2" : "=v"(r) : "v"(lo), "v"(hi));
    return r;
}

// ---------------- bucketed CSR build ----------------
__global__ __launch_bounds__(256) void bcount_kernel(const int* __restrict__ dst,
                                                     int* __restrict__ gcnt, int E) {
    __shared__ int hist[NBUCK];
    const int b = blockIdx.x;
    for (int i = threadIdx.x; i < NBUCK; i += 256) hist[i] = 0;
    __syncthreads();
    const int e0 = b * EPB;
    const int e1 = min(e0 + EPB, E);
    for (int e = e0 + threadIdx.x; e < e1; e += 256)
        atomicAdd(&hist[dst[e] >> 8], 1);
    __syncthreads();
    for (int q = threadIdx.x; q < NBUCK; q += 256)
        gcnt[q * NBLK + b] = hist[q];
}

// 3-phase exclusive scan (generic n)
__global__ __launch_bounds__(256) void scanA_kernel(const int* __restrict__ deg,
                                                    int* __restrict__ blk, int n) {
    __shared__ int red[4];
    const int i = blockIdx.x * 256 + threadIdx.x;
    int v = (i < n) ? deg[i] : 0;
    #pragma unroll
    for (int off = 32; off > 0; off >>= 1) v += __shfl_xor(v, off);
    if ((threadIdx.x & 63) == 0) red[threadIdx.x >> 6] = v;
    __syncthreads();
    if (threadIdx.x == 0) blk[blockIdx.x] = red[0] + red[1] + red[2] + red[3];
}

__global__ __launch_bounds__(256) void scanB_kernel(int* __restrict__ blk, int nb) {
    __shared__ int s[256];
    const int t = threadIdx.x;
    const int v = (t < nb) ? blk[t] : 0;
    s[t] = v;
    __syncthreads();
    for (int off = 1; off < 256; off <<= 1) {
        int u = (t >= off) ? s[t - off] : 0;
        __syncthreads();
        s[t] += u;
        __syncthreads();
    }
    if (t < nb) blk[t] = s[t] - v;  // exclusive
}

__global__ __launch_bounds__(256) void scanC_kernel(const int* __restrict__ deg,
                                                    const int* __restrict__ blk,
                                                    int* __restrict__ out, int n) {
    __shared__ int s[256];
    const int t = threadIdx.x;
    const int i = blockIdx.x * 256 + t;
    const int v = (i < n) ? deg[i] : 0;
    s[t] = v;
    __syncthreads();
    for (int off = 1; off < 256; off <<= 1) {
        int u = (t >= off) ? s[t - off] : 0;
        __syncthreads();
        s[t] += u;
        __syncthreads();
    }
    if (i <= n) out[i] = blk[blockIdx.x] + s[t] - v;
}

__global__ __launch_bounds__(256) void bscatter_kernel(const int* __restrict__ src,
                                                       const int* __restrict__ dst,
                                                       const int* __restrict__ roff,
                                                       unsigned* __restrict__ ebuf, int E) {
    __shared__ int cur[NBUCK];
    const int b = blockIdx.x;
    for (int q = threadIdx.x; q < NBUCK; q += 256) cur[q] = roff[q * NBLK + b];
    __syncthreads();
    const int e0 = b * EPB;
    const int e1 = min(e0 + EPB, E);
    for (int e = e0 + threadIdx.x; e < e1; e += 256) {
        const int d = dst[e];
        const int pos = atomicAdd(&cur[d >> 8], 1);
        ebuf[pos] = ((unsigned)(d & 255) << 16) | (unsigned)src[e];
    }
}

// one block per bucket: local CSR (contiguous csr region per bucket -> XCD-local writes)
__global__ __launch_bounds__(256) void bcsr_kernel(const unsigned* __restrict__ ebuf,
                                                   const int* __restrict__ roff,
                                                   int* __restrict__ csr_src,
                                                   int* __restrict__ row_ptr,
                                                   float* __restrict__ invd) {
    __shared__ int degs[256];
    __shared__ int scn[256];
    __shared__ int cur[256];
    const int q = blockIdx.x;
    const int t = threadIdx.x;
    const int start = roff[q * NBLK];
    const int end = (q == NBUCK - 1) ? NE : roff[(q + 1) * NBLK];
    degs[t] = 0;
    __syncthreads();
    for (int e = start + t; e < end; e += 256)
        atomicAdd(&degs[ebuf[e] >> 16], 1);
    __syncthreads();
    const int v = degs[t];
    scn[t] = v;
    __syncthreads();
    for (int off = 1; off < 256; off <<= 1) {
        int u = (t >= off) ? scn[t - off] : 0;
        __syncthreads();
        scn[t] += u;
        __syncthreads();
    }
    const int excl = scn[t] - v;
    cur[t] = start + excl;
    __syncthreads();
    for (int e = start + t; e < end; e += 256) {
        const unsigned p = ebuf[e];
        const int pos = atomicAdd(&cur[p >> 16], 1);
        csr_src[pos] = (int)(p & 0xffffu);
    }
    const int node = q * 256 + t;
    if (node < NN) {
        row_ptr[node] = start + excl;
        invd[node] = 1.0f / fmaxf((float)v, 1.0f);
    }
    if (q == NBUCK - 1 && t == 0) row_ptr[NN] = NE;
}

// ---------------- converts ----------------
__global__ void cvt_x_kernel(const float* __restrict__ in, ushort* __restrict__ outb,
                             unsigned* __restrict__ out8, int n4) {
    int i = blockIdx.x * blockDim.x + threadIdx.x;
    if (i >= n4) return;
    const float4 v = *reinterpret_cast<const float4*>(in + (size_t)i * 4);
    ushort4 o;
    o.x = f2b(v.x); o.y = f2b(v.y); o.z = f2b(v.z); o.w = f2b(v.w);
    *reinterpret_cast<ushort4*>(outb + (size_t)i * 4) = o;
    unsigned p = __builtin_amdgcn_cvt_pk_fp8_f32(v.x, v.y, 0, 0);
    p = __builtin_amdgcn_cvt_pk_fp8_f32(v.z, v.w, p, 1);
    out8[i] = p;
}

// in: [nmat][256][ncol] f32  ->  out: [nmat][ncol][256] bf16 (transposed per matrix)
__global__ void cvt_wt_kernel(const float* __restrict__ in, ushort* __restrict__ out,
                              int nmat, int ncol) {
    int idx = blockIdx.x * blockDim.x + threadIdx.x;
    int total = nmat * 256 * ncol;
    if (idx >= total) return;
    int k = idx & 255;
    int t = idx >> 8;
    int n = t % ncol;
    int m = t / ncol;
    out[idx] = f2b(in[(size_t)m * 256 * ncol + (size_t)k * ncol + n]);
}

// ---------------- gather-mean over fp8 rows -> fp8 agg (R8 structure) ----------------
// one wave per node; 4 groups of 16 lanes; group g handles neighbors i+g, i+4+g, i+8+g, i+12+g.
// Each lane reads one uint4 (16 fp8 = cols l16*16..+15) per row; HW cvt unpack; fp8 agg out.
__global__ __launch_bounds__(256) void gather_kernel(const unsigned char* __restrict__ h8,
                                                     const int* __restrict__ csr_src,
                                                     const int* __restrict__ row_ptr,
                                                     const float* __restrict__ invd,
                                                     unsigned char* __restrict__ agg8, int n) {
    const int node = blockIdx.x * 4 + (threadIdx.x >> 6);
    const int lane = threadIdx.x & 63;
    if (node >= n) return;
    const int beg = row_ptr[node];
    const int end = row_ptr[node + 1];
    const int g = lane >> 4;
    const int l16 = lane & 15;

    float a[16];
    #pragma unroll
    for (int j = 0; j < 16; ++j) a[j] = 0.f;

    int i = beg;
    for (; i + 15 < end; i += 16) {
        const int s0 = csr_src[i + g];
        const int s1 = csr_src[i + 4 + g];
        const int s2 = csr_src[i + 8 + g];
        const int s3 = csr_src[i + 12 + g];
        const uint4 v0 = *reinterpret_cast<const uint4*>(h8 + (size_t)s0 * D + l16 * 16);
        const uint4 v1 = *reinterpret_cast<const uint4*>(h8 + (size_t)s1 * D + l16 * 16);
        const uint4 v2 = *reinterpret_cast<const uint4*>(h8 + (size_t)s2 * D + l16 * 16);
        const uint4 v3 = *reinterpret_cast<const uint4*>(h8 + (size_t)s3 * D + l16 * 16);
        const unsigned w[16] = {v0.x, v0.y, v0.z, v0.w, v1.x, v1.y, v1.z, v1.w,
                                v2.x, v2.y, v2.z, v2.w, v3.x, v3.y, v3.z, v3.w};
        #pragma unroll
        for (int q = 0; q < 16; ++q) {
            const f32x2 lo = __builtin_amdgcn_cvt_pk_f32_fp8(w[q], 0);
            const f32x2 hi = __builtin_amdgcn_cvt_pk_f32_fp8(w[q], 1);
            const int b = (q & 3) * 4;
            a[b + 0] += lo.x; a[b + 1] += lo.y; a[b + 2] += hi.x; a[b + 3] += hi.y;
        }
    }
    #pragma unroll
    for (int t = 0; t < 4; ++t) {
        const int idx = i + 4 * t + g;
        if (idx < end) {
            const int s = csr_src[idx];
            const uint4 v = *reinterpret_cast<const uint4*>(h8 + (size_t)s * D + l16 * 16);
            const unsigned w[4] = {v.x, v.y, v.z, v.w};
            #pragma unroll
            for (int q = 0; q < 4; ++q) {
                const f32x2 lo = __builtin_amdgcn_cvt_pk_f32_fp8(w[q], 0);
                const f32x2 hi = __builtin_amdgcn_cvt_pk_f32_fp8(w[q], 1);
                a[4 * q + 0] += lo.x; a[4 * q + 1] += lo.y;
                a[4 * q + 2] += hi.x; a[4 * q + 3] += hi.y;
            }
        }
    }
    // reduce across the 4 groups (same l16 -> same columns)
    #pragma unroll
    for (int j = 0; j < 16; ++j) {
        a[j] += __shfl_xor(a[j], 16);
        a[j] += __shfl_xor(a[j], 32);
    }
    if (g == 0) {
        const float sc = invd[node];
        unsigned p[4];
        #pragma unroll
        for (int q = 0; q < 4; ++q) {
            unsigned r = __builtin_amdgcn_cvt_pk_fp8_f32(a[4 * q] * sc, a[4 * q + 1] * sc, 0, 0);
            r = __builtin_amdgcn_cvt_pk_fp8_f32(a[4 * q + 2] * sc, a[4 * q + 3] * sc, r, 1);
            p[q] = r;
        }
        uint4 o = {p[0], p[1], p[2], p[3]};
        *reinterpret_cast<uint4*>(agg8 + (size_t)node * D + l16 * 16) = o;
    }
}

// ---------------- bf16 MFMA GEMM, 128 rows x 256 cols per block, 512 threads ----------------
// A0F8: A0 operand is fp8 (converted to bf16 in staging; LDS/MFMA unchanged).
template <bool DUAL, bool RELU, bool OUTBF, bool OUT8, bool A0F8>
__global__ __launch_bounds__(512) void mgemm256_kernel(
    const unsigned char* __restrict__ A08, const ushort* __restrict__ A0b,
    const ushort* __restrict__ A1,
    const ushort* __restrict__ B0T, const ushort* __restrict__ B1T,
    const float* __restrict__ bias, void* __restrict__ out,
    unsigned char* __restrict__ out8, int N)
{
    __shared__ ushort As[128][40];
    __shared__ ushort Bs[256][40];

    const int tid = threadIdx.x;
    const int wave = tid >> 6;
    const int lane = tid & 63;
    const int wm = wave >> 2;
    const int wn = wave & 3;
    const int l15 = lane & 15;
    const int l4 = lane >> 4;
    const int r0 = blockIdx.x * 128;

    const f32x4 zero = {0.f, 0.f, 0.f, 0.f};
    f32x4 acc[4][4];
    #pragma unroll
    for (int i = 0; i < 4; ++i)
        #pragma unroll
        for (int j = 0; j < 4; ++j) acc[i][j] = zero;

    const int arr = tid >> 2;
    const int ach = (tid & 3) * 8;
    const int agrow = min(r0 + arr, N - 1);

    const int NT = DUAL ? 16 : 8;
    for (int kt = 0; kt < NT; ++kt) {
        const bool second = DUAL && (kt >= 8);
        const ushort* BT = second ? B1T : B0T;
        const int kb = (second ? (kt - 8) : kt) * 32;

        if (!second && A0F8) {
            const uint2 q = *reinterpret_cast<const uint2*>(A08 + (size_t)agrow * 256 + kb + ach);
            const f32x2 f0 = __builtin_amdgcn_cvt_pk_f32_fp8(q.x, 0);
            const f32x2 f1 = __builtin_amdgcn_cvt_pk_f32_fp8(q.x, 1);
            const f32x2 f2 = __builtin_amdgcn_cvt_pk_f32_fp8(q.y, 0);
            const f32x2 f3 = __builtin_amdgcn_cvt_pk_f32_fp8(q.y, 1);
            uint4 o;
            o.x = cvt2bf(f0.x, f0.y);
            o.y = cvt2bf(f1.x, f1.y);
            o.z = cvt2bf(f2.x, f2.y);
            o.w = cvt2bf(f3.x, f3.y);
            *reinterpret_cast<uint4*>(&As[arr][ach]) = o;
        } else {
            const ushort* A = second ? A1 : A0b;
            *reinterpret_cast<float4*>(&As[arr][ach]) =
                *reinterpret_cast<const float4*>(A + (size_t)agrow * 256 + kb + ach);
        }
        #pragma unroll
        for (int it = 0; it < 2; ++it) {
            const int idx = it * 512 + tid;
            const int br = idx >> 2;
            const int ch = (idx & 3) * 8;
            *reinterpret_cast<float4*>(&Bs[br][ch]) =
                *reinterpret_cast<const float4*>(BT + (size_t)br * 256 + kb + ch);
        }
        __syncthreads();

        bf16x8 af[4], bfr[4];
        #pragma unroll
        for (int i = 0; i < 4; ++i)
            af[i] = *reinterpret_cast<const bf16x8*>(&As[wm * 64 + 16 * i + l15][l4 * 8]);
        #pragma unroll
        for (int j = 0; j < 4; ++j)
            bfr[j] = *reinterpret_cast<const bf16x8*>(&Bs[wn * 64 + 16 * j + l15][l4 * 8]);
        #pragma unroll
        for (int i = 0; i < 4; ++i)
            #pragma unroll
            for (int j = 0; j < 4; ++j)
                acc[i][j] = __builtin_amdgcn_mfma_f32_16x16x32_bf16(af[i], bfr[j], acc[i][j], 0, 0, 0);
        __syncthreads();
    }

    const int rbase = r0 + wm * 64;
    const int cbase = wn * 64;
    #pragma unroll
    for (int i = 0; i < 4; ++i) {
        #pragma unroll
        for (int r = 0; r < 4; ++r) {
            const int row = rbase + 16 * i + l4 * 4 + r;
            if (row < N) {
                #pragma unroll
                for (int j = 0; j < 4; ++j) {
                    const int col = cbase + 16 * j + l15;
                    float v = acc[i][j][r] + bias[col];
                    if (RELU) v = fmaxf(v, 0.f);
                    if (OUTBF)
                        ((ushort*)out)[(size_t)row * 256 + col] = f2b(v);
                    else
                        ((float*)out)[(size_t)row * 256 + col] = v;
                    if (OUT8)
                        out8[(size_t)row * 256 + col] = f2fp8(v);
                }
            }
        }
    }
}

// ---------------- final GEMM (128 cols) with fused log-softmax ----------------
__global__ __launch_bounds__(256) void mgemm128sm_kernel(
    const ushort* __restrict__ A0, const ushort* __restrict__ B0T,
    const float* __restrict__ bias, float* __restrict__ out, int N)
{
    __shared__ ushort As[128][40];
    __shared__ ushort Bs[128][40];
    __shared__ float msh[2][128];
    __shared__ float ssh[2][128];

    const int tid = threadIdx.x;
    const int wave = tid >> 6;
    const int lane = tid & 63;
    const int wm = wave >> 1;
    const int wn = wave & 1;
    const int l15 = lane & 15;
    const int l4 = lane >> 4;
    const int r0 = blockIdx.x * 128;

    const f32x4 zero = {0.f, 0.f, 0.f, 0.f};
    f32x4 acc[4][4];
    #pragma unroll
    for (int i = 0; i < 4; ++i)
        #pragma unroll
        for (int j = 0; j < 4; ++j) acc[i][j] = zero;

    for (int kt = 0; kt < 8; ++kt) {
        const int kb = kt * 32;
        #pragma unroll
        for (int it = 0; it < 2; ++it) {
            const int idx = it * 256 + tid;
            const int rr = idx >> 2;
            const int ch = (idx & 3) * 8;
            const int grow = min(r0 + rr, N - 1);
            *reinterpret_cast<float4*>(&As[rr][ch]) =
                *reinterpret_cast<const float4*>(A0 + (size_t)grow * 256 + kb + ch);
            *reinterpret_cast<float4*>(&Bs[rr][ch]) =
                *reinterpret_cast<const float4*>(B0T + (size_t)rr * 256 + kb + ch);
        }
        __syncthreads();

        bf16x8 af[4], bfr[4];
        #pragma unroll
        for (int i = 0; i < 4; ++i)
            af[i] = *reinterpret_cast<const bf16x8*>(&As[wm * 64 + 16 * i + l15][l4 * 8]);
        #pragma unroll
        for (int j = 0; j < 4; ++j)
            bfr[j] = *reinterpret_cast<const bf16x8*>(&Bs[wn * 64 + 16 * j + l15][l4 * 8]);
        #pragma unroll
        for (int i = 0; i < 4; ++i)
            #pragma unroll
            for (int j = 0; j < 4; ++j)
                acc[i][j] = __builtin_amdgcn_mfma_f32_16x16x32_bf16(af[i], bfr[j], acc[i][j], 0, 0, 0);
        __syncthreads();
    }

    const int cbase = wn * 64;
    float bb[4];
    #pragma unroll
    for (int j = 0; j < 4; ++j) bb[j] = bias[cbase + 16 * j + l15];

    #pragma unroll
    for (int i = 0; i < 4; ++i) {
        #pragma unroll
        for (int r = 0; r < 4; ++r) {
            float v0 = acc[i][0][r] + bb[0];
            float v1 = acc[i][1][r] + bb[1];
            float v2 = acc[i][2][r] + bb[2];
            float v3 = acc[i][3][r] + bb[3];
            float m = fmaxf(fmaxf(v0, v1), fmaxf(v2, v3));
            #pragma unroll
            for (int off = 8; off > 0; off >>= 1) m = fmaxf(m, __shfl_xor(m, off));
            float s = expf(v0 - m) + expf(v1 - m) + expf(v2 - m) + expf(v3 - m);
            #pragma unroll
            for (int off = 8; off > 0; off >>= 1) s += __shfl_xor(s, off);
            if (l15 == 0) {
                const int lr = wm * 64 + 16 * i + l4 * 4 + r;
                msh[wn][lr] = m;
                ssh[wn][lr] = s;
            }
        }
    }
    __syncthreads();

    #pragma unroll
    for (int i = 0; i < 4; ++i) {
        #pragma unroll
        for (int r = 0; r < 4; ++r) {
            const int lr = wm * 64 + 16 * i + l4 * 4 + r;
            const float m0 = msh[0][lr], m1 = msh[1][lr];
            const float s0 = ssh[0][lr], s1 = ssh[1][lr];
            const float M = fmaxf(m0, m1);
            const float ls = M + logf(s0 * expf(m0 - M) + s1 * expf(m1 - M));
            const int row = r0 + lr;
            if (row < N) {
                #pragma unroll
                for (int j = 0; j < 4; ++j)
                    out[(size_t)row * DOUT + cbase + 16 * j + l15] = acc[i][j][r] + bb[j] - ls;
            }
        }
    }
}

extern "C" void kernel_launch(void* const* d_in, const int* in_sizes, int n_in,
                              void* d_out, int out_size, void* d_ws, size_t ws_size,
                              hipStream_t stream) {
    const float* x  = (const float*)d_in[0];
    const int* ei   = (const int*)d_in[1];
    const float* wl = (const float*)d_in[2];
    const float* bl = (const float*)d_in[3];
    const float* wr = (const float*)d_in[4];
    const float* w1 = (const float*)d_in[5];
    const float* b1 = (const float*)d_in[6];
    const float* w2 = (const float*)d_in[7];
    const float* b2 = (const float*)d_in[8];
    const int* src = ei;
    const int* dst = ei + NE;

    // ---- workspace layout ----
    ushort* hx   = (ushort*)d_ws;                 // NN*D bf16
    ushort* hA   = hx + (size_t)NN * D;
    ushort* hB   = hA + (size_t)NN * D;
    ushort* wlT  = hB + (size_t)NN * D;           // 3*256*256
    ushort* wrT  = wlT + 3 * 256 * 256;
    ushort* w1T  = wrT + 3 * 256 * 256;
    ushort* w2T  = w1T + 256 * 256;               // 128*256
    unsigned char* h8x = (unsigned char*)(w2T + 128 * 256);  // NN*D fp8
    unsigned char* h8A = h8x + (size_t)NN * D;
    unsigned char* h8B = h8A + (size_t)NN * D;
    unsigned char* agg8 = h8B + (size_t)NN * D;   // NN*D fp8
    float* invd  = (float*)(agg8 + (size_t)NN * D);  // NN
    int* row_ptr = (int*)(invd + NN);               // NN+1
    int* csr_src = row_ptr + NN + 1;                // NE
    unsigned* ebuf = (unsigned*)(csr_src + NE);     // NE
    int* gcnt    = (int*)(ebuf + NE);               // NSCAN
    int* roff    = gcnt + NSCAN;                    // NSCAN+1
    int* blk     = roff + NSCAN + 1;                // 256
    float* outf  = (float*)d_out;

    // ---- CSR build (counting sort, XCD-local writes) ----
    const int NSB = (NSCAN + 256) / 256;  // 77
    bcount_kernel<<<NBLK, 256, 0, stream>>>(dst, gcnt, NE);
    scanA_kernel<<<NSB, 256, 0, stream>>>(gcnt, blk, NSCAN);
    scanB_kernel<<<1, 256, 0, stream>>>(blk, NSB);
    scanC_kernel<<<NSB, 256, 0, stream>>>(gcnt, blk, roff, NSCAN);
    bscatter_kernel<<<NBLK, 256, 0, stream>>>(src, dst, roff, ebuf, NE);
    bcsr_kernel<<<NBUCK, 256, 0, stream>>>(ebuf, roff, csr_src, row_ptr, invd);

    // ---- converts ----
    cvt_x_kernel<<<(NN * D / 4 + 255) / 256, 256, 0, stream>>>(x, hx, (unsigned*)h8x, NN * D / 4);
    cvt_wt_kernel<<<(3 * 256 * 256 + 255) / 256, 256, 0, stream>>>(wl, wlT, 3, 256);
    cvt_wt_kernel<<<(3 * 256 * 256 + 255) / 256, 256, 0, stream>>>(wr, wrT, 3, 256);
    cvt_wt_kernel<<<(256 * 256 + 255) / 256, 256, 0, stream>>>(w1, w1T, 1, 256);
    cvt_wt_kernel<<<(128 * 256 + 255) / 256, 256, 0, stream>>>(w2, w2T, 1, 128);

    const int gpan = (NN + 127) / 128;
    const int gg = (NN + 3) / 4;

    // layer 0: gather(h8x)->agg8 ; DUAL(agg8 fp8, hx) -> hA (+h8A)
    gather_kernel<<<gg, 256, 0, stream>>>(h8x, csr_src, row_ptr, invd, agg8, NN);
    mgemm256_kernel<true, true, true, true, true><<<gpan, 512, 0, stream>>>(
        agg8, nullptr, hx, wlT, wrT, bl, hA, h8A, NN);
    // layer 1
    gather_kernel<<<gg, 256, 0, stream>>>(h8A, csr_src, row_ptr, invd, agg8, NN);
    mgemm256_kernel<true, true, true, true, true><<<gpan, 512, 0, stream>>>(
        agg8, nullptr, hA, wlT + 256 * 256, wrT + 256 * 256, bl + 256, hB, h8B, NN);
    // layer 2 (no fp8 output needed)
    gather_kernel<<<gg, 256, 0, stream>>>(h8B, csr_src, row_ptr, invd, agg8, NN);
    mgemm256_kernel<true, true, true, false, true><<<gpan, 512, 0, stream>>>(
        agg8, nullptr, hB, wlT + 2 * 256 * 256, wrT + 2 * 256 * 256, bl + 2 * 256, hA, nullptr, NN);
    // post-mp
    mgemm256_kernel<false, false, true, false, false><<<gpan, 512, 0, stream>>>(
        nullptr, hA, nullptr, w1T, nullptr, b1, hB, nullptr, NN);
    mgemm128sm_kernel<<<gpan, 256, 0, stream>>>(hB, w2T, b2, outf, NN);
}

// Round 12
// 326.244 us; speedup vs baseline: 1.3836x; 1.0162x over previous
//
#include <hip/hip_runtime.h>

#define NN 50000
#define NE 800000
#define D 256
#define DOUT 128

// bucket sort params: 196 buckets of 256 nodes; 98 blocks of 8192 edges
#define NBUCK 196
#define EPB 8192
#define NBLK 98
#define NSCAN (NBUCK * NBLK)  // 19208

typedef __attribute__((ext_vector_type(8))) short bf16x8;
typedef __attribute__((ext_vector_type(8))) ushort u16x8;
typedef __attribute__((ext_vector_type(4))) float f32x4;
typedef __attribute__((ext_vector_type(2))) float f32x2;

__device__ __forceinline__ ushort f2b(float f) {
    union { float f; unsigned u; } v; v.f = f;
    unsigned u = v.u + 0x7fffu + ((v.u >> 16) & 1u);
    return (ushort)(u >> 16);
}
__device__ __forceinline__ unsigned char f2fp8(float f) {
    return (unsigned char)(__builtin_amdgcn_cvt_pk_fp8_f32(f, 0.f, 0, 0) & 0xff);
}
// two f32 -> packed 2x bf16 in one instr (no builtin on gfx950)
__device__ __forceinline__ unsigned cvt2bf(float lo, float hi) {
    unsigned r;
    asm volatile("v_cvt_pk_bf16_f32 %0, %1, %2" : "=v"(r) : "v"(lo), "v"(hi));
    return r;
}

// ---------------- bucketed CSR build ----------------
__global__ __launch_bounds__(256) void bcount_kernel(const int* __restrict__ dst,
                                                     int* __restrict__ gcnt, int E) {
    __shared__ int hist[NBUCK];
    const int b = blockIdx.x;
    for (int i = threadIdx.x; i < NBUCK; i += 256) hist[i] = 0;
    __syncthreads();
    const int e0 = b * EPB;
    const int e1 = min(e0 + EPB, E);
    for (int e = e0 + threadIdx.x; e < e1; e += 256)
        atomicAdd(&hist[dst[e] >> 8], 1);
    __syncthreads();
    for (int q = threadIdx.x; q < NBUCK; q += 256)
        gcnt[q * NBLK + b] = hist[q];
}

// 3-phase exclusive scan (generic n)
__global__ __launch_bounds__(256) void scanA_kernel(const int* __restrict__ deg,
                                                    int* __restrict__ blk, int n) {
    __shared__ int red[4];
    const int i = blockIdx.x * 256 + threadIdx.x;
    int v = (i < n) ? deg[i] : 0;
    #pragma unroll
    for (int off = 32; off > 0; off >>= 1) v += __shfl_xor(v, off);
    if ((threadIdx.x & 63) == 0) red[threadIdx.x >> 6] = v;
    __syncthreads();
    if (threadIdx.x == 0) blk[blockIdx.x] = red[0] + red[1] + red[2] + red[3];
}

__global__ __launch_bounds__(256) void scanB_kernel(int* __restrict__ blk, int nb) {
    __shared__ int s[256];
    const int t = threadIdx.x;
    const int v = (t < nb) ? blk[t] : 0;
    s[t] = v;
    __syncthreads();
    for (int off = 1; off < 256; off <<= 1) {
        int u = (t >= off) ? s[t - off] : 0;
        __syncthreads();
        s[t] += u;
        __syncthreads();
    }
    if (t < nb) blk[t] = s[t] - v;  // exclusive
}

__global__ __launch_bounds__(256) void scanC_kernel(const int* __restrict__ deg,
                                                    const int* __restrict__ blk,
                                                    int* __restrict__ out, int n) {
    __shared__ int s[256];
    const int t = threadIdx.x;
    const int i = blockIdx.x * 256 + t;
    const int v = (i < n) ? deg[i] : 0;
    s[t] = v;
    __syncthreads();
    for (int off = 1; off < 256; off <<= 1) {
        int u = (t >= off) ? s[t - off] : 0;
        __syncthreads();
        s[t] += u;
        __syncthreads();
    }
    if (i <= n) out[i] = blk[blockIdx.x] + s[t] - v;
}

__global__ __launch_bounds__(256) void bscatter_kernel(const int* __restrict__ src,
                                                       const int* __restrict__ dst,
                                                       const int* __restrict__ roff,
                                                       unsigned* __restrict__ ebuf, int E) {
    __shared__ int cur[NBUCK];
    const int b = blockIdx.x;
    for (int q = threadIdx.x; q < NBUCK; q += 256) cur[q] = roff[q * NBLK + b];
    __syncthreads();
    const int e0 = b * EPB;
    const int e1 = min(e0 + EPB, E);
    for (int e = e0 + threadIdx.x; e < e1; e += 256) {
        const int d = dst[e];
        const int pos = atomicAdd(&cur[d >> 8], 1);
        ebuf[pos] = ((unsigned)(d & 255) << 16) | (unsigned)src[e];
    }
}

// one block per bucket: local CSR (contiguous csr region per bucket -> XCD-local writes)
__global__ __launch_bounds__(256) void bcsr_kernel(const unsigned* __restrict__ ebuf,
                                                   const int* __restrict__ roff,
                                                   int* __restrict__ csr_src,
                                                   int* __restrict__ row_ptr,
                                                   float* __restrict__ invd) {
    __shared__ int degs[256];
    __shared__ int scn[256];
    __shared__ int cur[256];
    const int q = blockIdx.x;
    const int t = threadIdx.x;
    const int start = roff[q * NBLK];
    const int end = (q == NBUCK - 1) ? NE : roff[(q + 1) * NBLK];
    degs[t] = 0;
    __syncthreads();
    for (int e = start + t; e < end; e += 256)
        atomicAdd(&degs[ebuf[e] >> 16], 1);
    __syncthreads();
    const int v = degs[t];
    scn[t] = v;
    __syncthreads();
    for (int off = 1; off < 256; off <<= 1) {
        int u = (t >= off) ? scn[t - off] : 0;
        __syncthreads();
        scn[t] += u;
        __syncthreads();
    }
    const int excl = scn[t] - v;
    cur[t] = start + excl;
    __syncthreads();
    for (int e = start + t; e < end; e += 256) {
        const unsigned p = ebuf[e];
        const int pos = atomicAdd(&cur[p >> 16], 1);
        csr_src[pos] = (int)(p & 0xffffu);
    }
    const int node = q * 256 + t;
    if (node < NN) {
        row_ptr[node] = start + excl;
        invd[node] = 1.0f / fmaxf((float)v, 1.0f);
    }
    if (q == NBUCK - 1 && t == 0) row_ptr[NN] = NE;
}

// ---------------- converts ----------------
__global__ void cvt_x_kernel(const float* __restrict__ in, ushort* __restrict__ outb,
                             unsigned* __restrict__ out8, int n4) {
    int i = blockIdx.x * blockDim.x + threadIdx.x;
    if (i >= n4) return;
    const float4 v = *reinterpret_cast<const float4*>(in + (size_t)i * 4);
    ushort4 o;
    o.x = f2b(v.x); o.y = f2b(v.y); o.z = f2b(v.z); o.w = f2b(v.w);
    *reinterpret_cast<ushort4*>(outb + (size_t)i * 4) = o;
    unsigned p = __builtin_amdgcn_cvt_pk_fp8_f32(v.x, v.y, 0, 0);
    p = __builtin_amdgcn_cvt_pk_fp8_f32(v.z, v.w, p, 1);
    out8[i] = p;
}

// all weights f32 -> transposed bf16, one launch. Regions: wl(3x256x256) wr(3x256x256)
// w1(256x256) w2(256x128). out[m][n][k] = in[m][k][n].
__global__ void cvt_w_kernel(const float* __restrict__ wl, const float* __restrict__ wr,
                             const float* __restrict__ w1, const float* __restrict__ w2,
                             ushort* __restrict__ wlT, ushort* __restrict__ wrT,
                             ushort* __restrict__ w1T, ushort* __restrict__ w2T) {
    int idx = blockIdx.x * 256 + threadIdx.x;
    const float* in; ushort* out; int ncol; int rel;
    if (idx < 196608)       { in = wl; out = wlT; ncol = 256; rel = idx; }
    else if (idx < 393216)  { in = wr; out = wrT; ncol = 256; rel = idx - 196608; }
    else if (idx < 458752)  { in = w1; out = w1T; ncol = 256; rel = idx - 393216; }
    else                    { in = w2; out = w2T; ncol = 128; rel = idx - 458752; }
    const int k = rel & 255;
    const int t = rel >> 8;
    const int n = t % ncol;
    const int m = t / ncol;
    out[rel] = f2b(in[(size_t)m * 256 * ncol + (size_t)k * ncol + n]);
}

// ---------------- gather-mean over fp8 rows -> fp8 agg (R8/R11 structure) ----------------
__global__ __launch_bounds__(256) void gather_kernel(const unsigned char* __restrict__ h8,
                                                     const int* __restrict__ csr_src,
                                                     const int* __restrict__ row_ptr,
                                                     const float* __restrict__ invd,
                                                     unsigned char* __restrict__ agg8, int n) {
    const int node = blockIdx.x * 4 + (threadIdx.x >> 6);
    const int lane = threadIdx.x & 63;
    if (node >= n) return;
    const int beg = row_ptr[node];
    const int end = row_ptr[node + 1];
    const int g = lane >> 4;
    const int l16 = lane & 15;

    float a[16];
    #pragma unroll
    for (int j = 0; j < 16; ++j) a[j] = 0.f;

    int i = beg;
    for (; i + 15 < end; i += 16) {
        const int s0 = csr_src[i + g];
        const int s1 = csr_src[i + 4 + g];
        const int s2 = csr_src[i + 8 + g];
        const int s3 = csr_src[i + 12 + g];
        const uint4 v0 = *reinterpret_cast<const uint4*>(h8 + (size_t)s0 * D + l16 * 16);
        const uint4 v1 = *reinterpret_cast<const uint4*>(h8 + (size_t)s1 * D + l16 * 16);
        const uint4 v2 = *reinterpret_cast<const uint4*>(h8 + (size_t)s2 * D + l16 * 16);
        const uint4 v3 = *reinterpret_cast<const uint4*>(h8 + (size_t)s3 * D + l16 * 16);
        const unsigned w[16] = {v0.x, v0.y, v0.z, v0.w, v1.x, v1.y, v1.z, v1.w,
                                v2.x, v2.y, v2.z, v2.w, v3.x, v3.y, v3.z, v3.w};
        #pragma unroll
        for (int q = 0; q < 16; ++q) {
            const f32x2 lo = __builtin_amdgcn_cvt_pk_f32_fp8(w[q], 0);
            const f32x2 hi = __builtin_amdgcn_cvt_pk_f32_fp8(w[q], 1);
            const int b = (q & 3) * 4;
            a[b + 0] += lo.x; a[b + 1] += lo.y; a[b + 2] += hi.x; a[b + 3] += hi.y;
        }
    }
    #pragma unroll
    for (int t = 0; t < 4; ++t) {
        const int idx = i + 4 * t + g;
        if (idx < end) {
            const int s = csr_src[idx];
            const uint4 v = *reinterpret_cast<const uint4*>(h8 + (size_t)s * D + l16 * 16);
            const unsigned w[4] = {v.x, v.y, v.z, v.w};
            #pragma unroll
            for (int q = 0; q < 4; ++q) {
                const f32x2 lo = __builtin_amdgcn_cvt_pk_f32_fp8(w[q], 0);
                const f32x2 hi = __builtin_amdgcn_cvt_pk_f32_fp8(w[q], 1);
                a[4 * q + 0] += lo.x; a[4 * q + 1] += lo.y;
                a[4 * q + 2] += hi.x; a[4 * q + 3] += hi.y;
            }
        }
    }
    // reduce across the 4 groups (same l16 -> same columns)
    #pragma unroll
    for (int j = 0; j < 16; ++j) {
        a[j] += __shfl_xor(a[j], 16);
        a[j] += __shfl_xor(a[j], 32);
    }
    if (g == 0) {
        const float sc = invd[node];
        unsigned p[4];
        #pragma unroll
        for (int q = 0; q < 4; ++q) {
            unsigned r = __builtin_amdgcn_cvt_pk_fp8_f32(a[4 * q] * sc, a[4 * q + 1] * sc, 0, 0);
            r = __builtin_amdgcn_cvt_pk_fp8_f32(a[4 * q + 2] * sc, a[4 * q + 3] * sc, r, 1);
            p[q] = r;
        }
        uint4 o = {p[0], p[1], p[2], p[3]};
        *reinterpret_cast<uint4*>(agg8 + (size_t)node * D + l16 * 16) = o;
    }
}

// ---------------- bf16 MFMA GEMM, 128 rows x 256 cols per block, 512 threads ----------------
// A0F8: A0 operand is fp8 (converted to bf16 in staging; LDS/MFMA unchanged).
template <bool DUAL, bool RELU, bool OUTBF, bool OUT8, bool A0F8>
__global__ __launch_bounds__(512) void mgemm256_kernel(
    const unsigned char* __restrict__ A08, const ushort* __restrict__ A0b,
    const ushort* __restrict__ A1,
    const ushort* __restrict__ B0T, const ushort* __restrict__ B1T,
    const float* __restrict__ bias, void* __restrict__ out,
    unsigned char* __restrict__ out8, int N)
{
    __shared__ ushort As[128][40];
    __shared__ ushort Bs[256][40];

    const int tid = threadIdx.x;
    const int wave = tid >> 6;
    const int lane = tid & 63;
    const int wm = wave >> 2;
    const int wn = wave & 3;
    const int l15 = lane & 15;
    const int l4 = lane >> 4;
    const int r0 = blockIdx.x * 128;

    const f32x4 zero = {0.f, 0.f, 0.f, 0.f};
    f32x4 acc[4][4];
    #pragma unroll
    for (int i = 0; i < 4; ++i)
        #pragma unroll
        for (int j = 0; j < 4; ++j) acc[i][j] = zero;

    const int arr = tid >> 2;
    const int ach = (tid & 3) * 8;
    const int agrow = min(r0 + arr, N - 1);

    const int NT = DUAL ? 16 : 8;
    for (int kt = 0; kt < NT; ++kt) {
        const bool second = DUAL && (kt >= 8);
        const ushort* BT = second ? B1T : B0T;
        const int kb = (second ? (kt - 8) : kt) * 32;

        if (!second && A0F8) {
            const uint2 q = *reinterpret_cast<const uint2*>(A08 + (size_t)agrow * 256 + kb + ach);
            const f32x2 f0 = __builtin_amdgcn_cvt_pk_f32_fp8(q.x, 0);
            const f32x2 f1 = __builtin_amdgcn_cvt_pk_f32_fp8(q.x, 1);
            const f32x2 f2 = __builtin_amdgcn_cvt_pk_f32_fp8(q.y, 0);
            const f32x2 f3 = __builtin_amdgcn_cvt_pk_f32_fp8(q.y, 1);
            uint4 o;
            o.x = cvt2bf(f0.x, f0.y);
            o.y = cvt2bf(f1.x, f1.y);
            o.z = cvt2bf(f2.x, f2.y);
            o.w = cvt2bf(f3.x, f3.y);
            *reinterpret_cast<uint4*>(&As[arr][ach]) = o;
        } else {
            const ushort* A = second ? A1 : A0b;
            *reinterpret_cast<float4*>(&As[arr][ach]) =
                *reinterpret_cast<const float4*>(A + (size_t)agrow * 256 + kb + ach);
        }
        #pragma unroll
        for (int it = 0; it < 2; ++it) {
            const int idx = it * 512 + tid;
            const int br = idx >> 2;
            const int ch = (idx & 3) * 8;
            *reinterpret_cast<float4*>(&Bs[br][ch]) =
                *reinterpret_cast<const float4*>(BT + (size_t)br * 256 + kb + ch);
        }
        __syncthreads();

        bf16x8 af[4], bfr[4];
        #pragma unroll
        for (int i = 0; i < 4; ++i)
            af[i] = *reinterpret_cast<const bf16x8*>(&As[wm * 64 + 16 * i + l15][l4 * 8]);
        #pragma unroll
        for (int j = 0; j < 4; ++j)
            bfr[j] = *reinterpret_cast<const bf16x8*>(&Bs[wn * 64 + 16 * j + l15][l4 * 8]);
        #pragma unroll
        for (int i = 0; i < 4; ++i)
            #pragma unroll
            for (int j = 0; j < 4; ++j)
                acc[i][j] = __builtin_amdgcn_mfma_f32_16x16x32_bf16(af[i], bfr[j], acc[i][j], 0, 0, 0);
        __syncthreads();
    }

    const int rbase = r0 + wm * 64;
    const int cbase = wn * 64;
    #pragma unroll
    for (int i = 0; i < 4; ++i) {
        #pragma unroll
        for (int r = 0; r < 4; ++r) {
            const int row = rbase + 16 * i + l4 * 4 + r;
            if (row < N) {
                #pragma unroll
                for (int j = 0; j < 4; ++j) {
                    const int col = cbase + 16 * j + l15;
                    float v = acc[i][j][r] + bias[col];
                    if (RELU) v = fmaxf(v, 0.f);
                    if (OUTBF)
                        ((ushort*)out)[(size_t)row * 256 + col] = f2b(v);
                    else
                        ((float*)out)[(size_t)row * 256 + col] = v;
                    if (OUT8)
                        out8[(size_t)row * 256 + col] = f2fp8(v);
                }
            }
        }
    }
}

// ---------------- fused post-MP: t1 = A@W1+b1 ; out = logsoftmax(t1@W2+b2) ----------------
// 512 threads, 128 rows/block. t1 (128x256 bf16) lives in LDS between the two GEMMs.
__global__ __launch_bounds__(512) void mlp_kernel(
    const ushort* __restrict__ A0, const ushort* __restrict__ W1T,
    const ushort* __restrict__ W2T,
    const float* __restrict__ b1, const float* __restrict__ b2,
    float* __restrict__ out, int N)
{
    __shared__ ushort As[128][40];
    __shared__ ushort Bs[256][40];
    __shared__ ushort T[128][264];   // 264-ushort stride: 2-way bank alias (free)
    __shared__ float msh[2][128];
    __shared__ float ssh[2][128];

    const int tid = threadIdx.x;
    const int wave = tid >> 6;
    const int lane = tid & 63;
    const int l15 = lane & 15;
    const int l4 = lane >> 4;
    const int r0 = blockIdx.x * 128;

    const f32x4 zero = {0.f, 0.f, 0.f, 0.f};

    // ---- phase 1: t1 = A0 @ W1 + b1  (128 x 256) ----
    {
        const int wm = wave >> 2;   // 0..1
        const int wn = wave & 3;    // 0..3
        f32x4 acc[4][4];
        #pragma unroll
        for (int i = 0; i < 4; ++i)
            #pragma unroll
            for (int j = 0; j < 4; ++j) acc[i][j] = zero;

        const int arr = tid >> 2;
        const int ach = (tid & 3) * 8;
        const int agrow = min(r0 + arr, N - 1);

        for (int kt = 0; kt < 8; ++kt) {
            const int kb = kt * 32;
            *reinterpret_cast<float4*>(&As[arr][ach]) =
                *reinterpret_cast<const float4*>(A0 + (size_t)agrow * 256 + kb + ach);
            #pragma unroll
            for (int it = 0; it < 2; ++it) {
                const int idx = it * 512 + tid;
                const int br = idx >> 2;
                const int ch = (idx & 3) * 8;
                *reinterpret_cast<float4*>(&Bs[br][ch]) =
                    *reinterpret_cast<const float4*>(W1T + (size_t)br * 256 + kb + ch);
            }
            __syncthreads();

            bf16x8 af[4], bfr[4];
            #pragma unroll
            for (int i = 0; i < 4; ++i)
                af[i] = *reinterpret_cast<const bf16x8*>(&As[wm * 64 + 16 * i + l15][l4 * 8]);
            #pragma unroll
            for (int j = 0; j < 4; ++j)
                bfr[j] = *reinterpret_cast<const bf16x8*>(&Bs[wn * 64 + 16 * j + l15][l4 * 8]);
            #pragma unroll
            for (int i = 0; i < 4; ++i)
                #pragma unroll
                for (int j = 0; j < 4; ++j)
                    acc[i][j] = __builtin_amdgcn_mfma_f32_16x16x32_bf16(af[i], bfr[j], acc[i][j], 0, 0, 0);
            __syncthreads();
        }

        // write t1 to LDS (bias, no relu)
        const int rbase = wm * 64;
        const int cbase = wn * 64;
        #pragma unroll
        for (int i = 0; i < 4; ++i) {
            #pragma unroll
            for (int r = 0; r < 4; ++r) {
                const int row = rbase + 16 * i + l4 * 4 + r;
                #pragma unroll
                for (int j = 0; j < 4; ++j) {
                    const int col = cbase + 16 * j + l15;
                    T[row][col] = f2b(acc[i][j][r] + b1[col]);
                }
            }
        }
    }
    __syncthreads();

    // ---- phase 2: t2 = t1 @ W2 + b2 (128 x 128), fused log-softmax ----
    {
        const int wm = wave >> 1;   // 0..3 (32 rows each)
        const int wn = wave & 1;    // 0..1 (64 cols each)
        f32x4 acc[2][4];
        #pragma unroll
        for (int i = 0; i < 2; ++i)
            #pragma unroll
            for (int j = 0; j < 4; ++j) acc[i][j] = zero;

        for (int kt = 0; kt < 8; ++kt) {
            const int kb = kt * 32;
            {   // stage W2T slice: 128 rows x 32 k -> 512 threads x 1 float4
                const int br = tid >> 2;
                const int ch = (tid & 3) * 8;
                *reinterpret_cast<float4*>(&Bs[br][ch]) =
                    *reinterpret_cast<const float4*>(W2T + (size_t)br * 256 + kb + ch);
            }
            __syncthreads();

            bf16x8 af[2], bfr[4];
            #pragma unroll
            for (int i = 0; i < 2; ++i)
                af[i] = *reinterpret_cast<const bf16x8*>(&T[wm * 32 + 16 * i + l15][kb + l4 * 8]);
            #pragma unroll
            for (int j = 0; j < 4; ++j)
                bfr[j] = *reinterpret_cast<const bf16x8*>(&Bs[wn * 64 + 16 * j + l15][l4 * 8]);
            #pragma unroll
            for (int i = 0; i < 2; ++i)
                #pragma unroll
                for (int j = 0; j < 4; ++j)
                    acc[i][j] = __builtin_amdgcn_mfma_f32_16x16x32_bf16(af[i], bfr[j], acc[i][j], 0, 0, 0);
            __syncthreads();
        }

        const int cbase = wn * 64;
        float bb[4];
        #pragma unroll
        for (int j = 0; j < 4; ++j) bb[j] = b2[cbase + 16 * j + l15];

        #pragma unroll
        for (int i = 0; i < 2; ++i) {
            #pragma unroll
            for (int r = 0; r < 4; ++r) {
                float v0 = acc[i][0][r] + bb[0];
                float v1 = acc[i][1][r] + bb[1];
                float v2 = acc[i][2][r] + bb[2];
                float v3 = acc[i][3][r] + bb[3];
                float m = fmaxf(fmaxf(v0, v1), fmaxf(v2, v3));
                #pragma unroll
                for (int off = 8; off > 0; off >>= 1) m = fmaxf(m, __shfl_xor(m, off));
                float s = expf(v0 - m) + expf(v1 - m) + expf(v2 - m) + expf(v3 - m);
                #pragma unroll
                for (int off = 8; off > 0; off >>= 1) s += __shfl_xor(s, off);
                if (l15 == 0) {
                    const int lr = wm * 32 + 16 * i + l4 * 4 + r;
                    msh[wn][lr] = m;
                    ssh[wn][lr] = s;
                }
            }
        }
        __syncthreads();

        #pragma unroll
        for (int i = 0; i < 2; ++i) {
            #pragma unroll
            for (int r = 0; r < 4; ++r) {
                const int lr = wm * 32 + 16 * i + l4 * 4 + r;
                const float m0 = msh[0][lr], m1 = msh[1][lr];
                const float s0 = ssh[0][lr], s1 = ssh[1][lr];
                const float M = fmaxf(m0, m1);
                const float ls = M + logf(s0 * expf(m0 - M) + s1 * expf(m1 - M));
                const int row = r0 + lr;
                if (row < N) {
                    #pragma unroll
                    for (int j = 0; j < 4; ++j)
                        out[(size_t)row * DOUT + cbase + 16 * j + l15] = acc[i][j][r] + bb[j] - ls;
                }
            }
        }
    }
}

extern "C" void kernel_launch(void* const* d_in, const int* in_sizes, int n_in,
                              void* d_out, int out_size, void* d_ws, size_t ws_size,
                              hipStream_t stream) {
    const float* x  = (const float*)d_in[0];
    const int* ei   = (const int*)d_in[1];
    const float* wl = (const float*)d_in[2];
    const float* bl = (const float*)d_in[3];
    const float* wr = (const float*)d_in[4];
    const float* w1 = (const float*)d_in[5];
    const float* b1 = (const float*)d_in[6];
    const float* w2 = (const float*)d_in[7];
    const float* b2 = (const float*)d_in[8];
    const int* src = ei;
    const int* dst = ei + NE;

    // ---- workspace layout ----
    ushort* hx   = (ushort*)d_ws;                 // NN*D bf16
    ushort* hA   = hx + (size_t)NN * D;
    ushort* hB   = hA + (size_t)NN * D;
    ushort* wlT  = hB + (size_t)NN * D;           // 3*256*256
    ushort* wrT  = wlT + 3 * 256 * 256;
    ushort* w1T  = wrT + 3 * 256 * 256;
    ushort* w2T  = w1T + 256 * 256;               // 128*256
    unsigned char* h8x = (unsigned char*)(w2T + 128 * 256);  // NN*D fp8
    unsigned char* h8A = h8x + (size_t)NN * D;
    unsigned char* h8B = h8A + (size_t)NN * D;
    unsigned char* agg8 = h8B + (size_t)NN * D;   // NN*D fp8
    float* invd  = (float*)(agg8 + (size_t)NN * D);  // NN
    int* row_ptr = (int*)(invd + NN);               // NN+1
    int* csr_src = row_ptr + NN + 1;                // NE
    unsigned* ebuf = (unsigned*)(csr_src + NE);     // NE
    int* gcnt    = (int*)(ebuf + NE);               // NSCAN
    int* roff    = gcnt + NSCAN;                    // NSCAN+1
    int* blk     = roff + NSCAN + 1;                // 256
    float* outf  = (float*)d_out;

    // ---- CSR build (counting sort, XCD-local writes) ----
    const int NSB = (NSCAN + 256) / 256;  // 77
    bcount_kernel<<<NBLK, 256, 0, stream>>>(dst, gcnt, NE);
    scanA_kernel<<<NSB, 256, 0, stream>>>(gcnt, blk, NSCAN);
    scanB_kernel<<<1, 256, 0, stream>>>(blk, NSB);
    scanC_kernel<<<NSB, 256, 0, stream>>>(gcnt, blk, roff, NSCAN);
    bscatter_kernel<<<NBLK, 256, 0, stream>>>(src, dst, roff, ebuf, NE);
    bcsr_kernel<<<NBUCK, 256, 0, stream>>>(ebuf, roff, csr_src, row_ptr, invd);

    // ---- converts ----
    cvt_x_kernel<<<(NN * D / 4 + 255) / 256, 256, 0, stream>>>(x, hx, (unsigned*)h8x, NN * D / 4);
    cvt_w_kernel<<<1920, 256, 0, stream>>>(wl, wr, w1, w2, wlT, wrT, w1T, w2T);

    const int gpan = (NN + 127) / 128;
    const int gg = (NN + 3) / 4;

    // layer 0: gather(h8x)->agg8 ; DUAL(agg8 fp8, hx) -> hA (+h8A)
    gather_kernel<<<gg, 256, 0, stream>>>(h8x, csr_src, row_ptr, invd, agg8, NN);
    mgemm256_kernel<true, true, true, true, true><<<gpan, 512, 0, stream>>>(
        agg8, nullptr, hx, wlT, wrT, bl, hA, h8A, NN);
    // layer 1
    gather_kernel<<<gg, 256, 0, stream>>>(h8A, csr_src, row_ptr, invd, agg8, NN);
    mgemm256_kernel<true, true, true, true, true><<<gpan, 512, 0, stream>>>(
        agg8, nullptr, hA, wlT + 256 * 256, wrT + 256 * 256, bl + 256, hB, h8B, NN);
    // layer 2 (no fp8 output needed)
    gather_kernel<<<gg, 256, 0, stream>>>(h8B, csr_src, row_ptr, invd, agg8, NN);
    mgemm256_kernel<true, true, true, false, true><<<gpan, 512, 0, stream>>>(
        agg8, nullptr, hB, wlT + 2 * 256 * 256, wrT + 2 * 256 * 256, bl + 2 * 256, hA, nullptr, NN);
    // fused post-MP (mp1 + mp2 + log-softmax)
    mlp_kernel<<<gpan, 512, 0, stream>>>(hA, w1T, w2T, b1, b2, outf, NN);
}

// Round 13
// 312.768 us; speedup vs baseline: 1.4433x; 1.0431x over previous
//
#include <hip/hip_runtime.h>

#define NN 50000
#define NE 800000
#define D 256
#define DOUT 128

// bucket sort params: 196 buckets of 256 nodes; 98 blocks of 8192 edges
#define NBUCK 196
#define EPB 8192
#define NBLK 98
#define NSCAN (NBUCK * NBLK)  // 19208

typedef __attribute__((ext_vector_type(8))) short bf16x8;
typedef __attribute__((ext_vector_type(8))) ushort u16x8;
typedef __attribute__((ext_vector_type(4))) float f32x4;
typedef __attribute__((ext_vector_type(2))) float f32x2;

__device__ __forceinline__ ushort f2b(float f) {
    union { float f; unsigned u; } v; v.f = f;
    unsigned u = v.u + 0x7fffu + ((v.u >> 16) & 1u);
    return (ushort)(u >> 16);
}
__device__ __forceinline__ unsigned char f2fp8(float f) {
    return (unsigned char)(__builtin_amdgcn_cvt_pk_fp8_f32(f, 0.f, 0, 0) & 0xff);
}
// two f32 -> packed 2x bf16 in one instr (no builtin on gfx950)
__device__ __forceinline__ unsigned cvt2bf(float lo, float hi) {
    unsigned r;
    asm volatile("v_cvt_pk_bf16_f32 %0, %1, %2" : "=v"(r) : "v"(lo), "v"(hi));
    return r;
}

// ---------------- bucketed CSR build ----------------
__global__ __launch_bounds__(256) void bcount_kernel(const int* __restrict__ dst,
                                                     int* __restrict__ gcnt, int E) {
    __shared__ int hist[NBUCK];
    const int b = blockIdx.x;
    for (int i = threadIdx.x; i < NBUCK; i += 256) hist[i] = 0;
    __syncthreads();
    const int e0 = b * EPB;
    const int e1 = min(e0 + EPB, E);
    for (int e = e0 + threadIdx.x; e < e1; e += 256)
        atomicAdd(&hist[dst[e] >> 8], 1);
    __syncthreads();
    for (int q = threadIdx.x; q < NBUCK; q += 256)
        gcnt[q * NBLK + b] = hist[q];
}

// 3-phase exclusive scan (generic n)
__global__ __launch_bounds__(256) void scanA_kernel(const int* __restrict__ deg,
                                                    int* __restrict__ blk, int n) {
    __shared__ int red[4];
    const int i = blockIdx.x * 256 + threadIdx.x;
    int v = (i < n) ? deg[i] : 0;
    #pragma unroll
    for (int off = 32; off > 0; off >>= 1) v += __shfl_xor(v, off);
    if ((threadIdx.x & 63) == 0) red[threadIdx.x >> 6] = v;
    __syncthreads();
    if (threadIdx.x == 0) blk[blockIdx.x] = red[0] + red[1] + red[2] + red[3];
}

__global__ __launch_bounds__(256) void scanB_kernel(int* __restrict__ blk, int nb) {
    __shared__ int s[256];
    const int t = threadIdx.x;
    const int v = (t < nb) ? blk[t] : 0;
    s[t] = v;
    __syncthreads();
    for (int off = 1; off < 256; off <<= 1) {
        int u = (t >= off) ? s[t - off] : 0;
        __syncthreads();
        s[t] += u;
        __syncthreads();
    }
    if (t < nb) blk[t] = s[t] - v;  // exclusive
}

__global__ __launch_bounds__(256) void scanC_kernel(const int* __restrict__ deg,
                                                    const int* __restrict__ blk,
                                                    int* __restrict__ out, int n) {
    __shared__ int s[256];
    const int t = threadIdx.x;
    const int i = blockIdx.x * 256 + t;
    const int v = (i < n) ? deg[i] : 0;
    s[t] = v;
    __syncthreads();
    for (int off = 1; off < 256; off <<= 1) {
        int u = (t >= off) ? s[t - off] : 0;
        __syncthreads();
        s[t] += u;
        __syncthreads();
    }
    if (i <= n) out[i] = blk[blockIdx.x] + s[t] - v;
}

__global__ __launch_bounds__(256) void bscatter_kernel(const int* __restrict__ src,
                                                       const int* __restrict__ dst,
                                                       const int* __restrict__ roff,
                                                       unsigned* __restrict__ ebuf, int E) {
    __shared__ int cur[NBUCK];
    const int b = blockIdx.x;
    for (int q = threadIdx.x; q < NBUCK; q += 256) cur[q] = roff[q * NBLK + b];
    __syncthreads();
    const int e0 = b * EPB;
    const int e1 = min(e0 + EPB, E);
    for (int e = e0 + threadIdx.x; e < e1; e += 256) {
        const int d = dst[e];
        const int pos = atomicAdd(&cur[d >> 8], 1);
        ebuf[pos] = ((unsigned)(d & 255) << 16) | (unsigned)src[e];
    }
}

// one block per bucket: local CSR (contiguous csr region per bucket -> XCD-local writes)
__global__ __launch_bounds__(256) void bcsr_kernel(const unsigned* __restrict__ ebuf,
                                                   const int* __restrict__ roff,
                                                   int* __restrict__ csr_src,
                                                   int* __restrict__ row_ptr,
                                                   float* __restrict__ invd) {
    __shared__ int degs[256];
    __shared__ int scn[256];
    __shared__ int cur[256];
    const int q = blockIdx.x;
    const int t = threadIdx.x;
    const int start = roff[q * NBLK];
    const int end = (q == NBUCK - 1) ? NE : roff[(q + 1) * NBLK];
    degs[t] = 0;
    __syncthreads();
    for (int e = start + t; e < end; e += 256)
        atomicAdd(&degs[ebuf[e] >> 16], 1);
    __syncthreads();
    const int v = degs[t];
    scn[t] = v;
    __syncthreads();
    for (int off = 1; off < 256; off <<= 1) {
        int u = (t >= off) ? scn[t - off] : 0;
        __syncthreads();
        scn[t] += u;
        __syncthreads();
    }
    const int excl = scn[t] - v;
    cur[t] = start + excl;
    __syncthreads();
    for (int e = start + t; e < end; e += 256) {
        const unsigned p = ebuf[e];
        const int pos = atomicAdd(&cur[p >> 16], 1);
        csr_src[pos] = (int)(p & 0xffffu);
    }
    const int node = q * 256 + t;
    if (node < NN) {
        row_ptr[node] = start + excl;
        invd[node] = 1.0f / fmaxf((float)v, 1.0f);
    }
    if (q == NBUCK - 1 && t == 0) row_ptr[NN] = NE;
}

// ---------------- converts ----------------
// x f32 -> fp8 only
__global__ void cvt_x_kernel(const float* __restrict__ in, unsigned* __restrict__ out8, int n4) {
    int i = blockIdx.x * blockDim.x + threadIdx.x;
    if (i >= n4) return;
    const float4 v = *reinterpret_cast<const float4*>(in + (size_t)i * 4);
    unsigned p = __builtin_amdgcn_cvt_pk_fp8_f32(v.x, v.y, 0, 0);
    p = __builtin_amdgcn_cvt_pk_fp8_f32(v.z, v.w, p, 1);
    out8[i] = p;
}

// all weights f32 -> transposed bf16, one launch.
__global__ void cvt_w_kernel(const float* __restrict__ wl, const float* __restrict__ wr,
                             const float* __restrict__ w1, const float* __restrict__ w2,
                             ushort* __restrict__ wlT, ushort* __restrict__ wrT,
                             ushort* __restrict__ w1T, ushort* __restrict__ w2T) {
    int idx = blockIdx.x * 256 + threadIdx.x;
    const float* in; ushort* out; int ncol; int rel;
    if (idx < 196608)       { in = wl; out = wlT; ncol = 256; rel = idx; }
    else if (idx < 393216)  { in = wr; out = wrT; ncol = 256; rel = idx - 196608; }
    else if (idx < 458752)  { in = w1; out = w1T; ncol = 256; rel = idx - 393216; }
    else                    { in = w2; out = w2T; ncol = 128; rel = idx - 458752; }
    const int k = rel & 255;
    const int t = rel >> 8;
    const int n = t % ncol;
    const int m = t / ncol;
    out[rel] = f2b(in[(size_t)m * 256 * ncol + (size_t)k * ncol + n]);
}

// ---------------- gather-mean over fp8 rows -> fp8 agg (R8/R11 structure) ----------------
__global__ __launch_bounds__(256) void gather_kernel(const unsigned char* __restrict__ h8,
                                                     const int* __restrict__ csr_src,
                                                     const int* __restrict__ row_ptr,
                                                     const float* __restrict__ invd,
                                                     unsigned char* __restrict__ agg8, int n) {
    const int node = blockIdx.x * 4 + (threadIdx.x >> 6);
    const int lane = threadIdx.x & 63;
    if (node >= n) return;
    const int beg = row_ptr[node];
    const int end = row_ptr[node + 1];
    const int g = lane >> 4;
    const int l16 = lane & 15;

    float a[16];
    #pragma unroll
    for (int j = 0; j < 16; ++j) a[j] = 0.f;

    int i = beg;
    for (; i + 15 < end; i += 16) {
        const int s0 = csr_src[i + g];
        const int s1 = csr_src[i + 4 + g];
        const int s2 = csr_src[i + 8 + g];
        const int s3 = csr_src[i + 12 + g];
        const uint4 v0 = *reinterpret_cast<const uint4*>(h8 + (size_t)s0 * D + l16 * 16);
        const uint4 v1 = *reinterpret_cast<const uint4*>(h8 + (size_t)s1 * D + l16 * 16);
        const uint4 v2 = *reinterpret_cast<const uint4*>(h8 + (size_t)s2 * D + l16 * 16);
        const uint4 v3 = *reinterpret_cast<const uint4*>(h8 + (size_t)s3 * D + l16 * 16);
        const unsigned w[16] = {v0.x, v0.y, v0.z, v0.w, v1.x, v1.y, v1.z, v1.w,
                                v2.x, v2.y, v2.z, v2.w, v3.x, v3.y, v3.z, v3.w};
        #pragma unroll
        for (int q = 0; q < 16; ++q) {
            const f32x2 lo = __builtin_amdgcn_cvt_pk_f32_fp8(w[q], 0);
            const f32x2 hi = __builtin_amdgcn_cvt_pk_f32_fp8(w[q], 1);
            const int b = (q & 3) * 4;
            a[b + 0] += lo.x; a[b + 1] += lo.y; a[b + 2] += hi.x; a[b + 3] += hi.y;
        }
    }
    #pragma unroll
    for (int t = 0; t < 4; ++t) {
        const int idx = i + 4 * t + g;
        if (idx < end) {
            const int s = csr_src[idx];
            const uint4 v = *reinterpret_cast<const uint4*>(h8 + (size_t)s * D + l16 * 16);
            const unsigned w[4] = {v.x, v.y, v.z, v.w};
            #pragma unroll
            for (int q = 0; q < 4; ++q) {
                const f32x2 lo = __builtin_amdgcn_cvt_pk_f32_fp8(w[q], 0);
                const f32x2 hi = __builtin_amdgcn_cvt_pk_f32_fp8(w[q], 1);
                a[4 * q + 0] += lo.x; a[4 * q + 1] += lo.y;
                a[4 * q + 2] += hi.x; a[4 * q + 3] += hi.y;
            }
        }
    }
    // reduce across the 4 groups (same l16 -> same columns)
    #pragma unroll
    for (int j = 0; j < 16; ++j) {
        a[j] += __shfl_xor(a[j], 16);
        a[j] += __shfl_xor(a[j], 32);
    }
    if (g == 0) {
        const float sc = invd[node];
        unsigned p[4];
        #pragma unroll
        for (int q = 0; q < 4; ++q) {
            unsigned r = __builtin_amdgcn_cvt_pk_fp8_f32(a[4 * q] * sc, a[4 * q + 1] * sc, 0, 0);
            r = __builtin_amdgcn_cvt_pk_fp8_f32(a[4 * q + 2] * sc, a[4 * q + 3] * sc, r, 1);
            p[q] = r;
        }
        uint4 o = {p[0], p[1], p[2], p[3]};
        *reinterpret_cast<uint4*>(agg8 + (size_t)node * D + l16 * 16) = o;
    }
}

// ---------------- bf16 MFMA DUAL GEMM, both A operands fp8, 128x256/block ----------------
// out = relu( bias + agg8@B0T^T + h8@B1T^T ); outputs bf16 (OUTBF) and/or fp8 (OUT8).
template <bool OUTBF, bool OUT8>
__global__ __launch_bounds__(512) void mgemm256f8_kernel(
    const unsigned char* __restrict__ A08, const unsigned char* __restrict__ A18,
    const ushort* __restrict__ B0T, const ushort* __restrict__ B1T,
    const float* __restrict__ bias, ushort* __restrict__ outb,
    unsigned char* __restrict__ out8, int N)
{
    __shared__ ushort As[128][40];
    __shared__ ushort Bs[256][40];

    const int tid = threadIdx.x;
    const int wave = tid >> 6;
    const int lane = tid & 63;
    const int wm = wave >> 2;
    const int wn = wave & 3;
    const int l15 = lane & 15;
    const int l4 = lane >> 4;
    const int r0 = blockIdx.x * 128;

    const f32x4 zero = {0.f, 0.f, 0.f, 0.f};
    f32x4 acc[4][4];
    #pragma unroll
    for (int i = 0; i < 4; ++i)
        #pragma unroll
        for (int j = 0; j < 4; ++j) acc[i][j] = zero;

    const int arr = tid >> 2;
    const int ach = (tid & 3) * 8;
    const int agrow = min(r0 + arr, N - 1);

    for (int kt = 0; kt < 16; ++kt) {
        const bool second = (kt >= 8);
        const unsigned char* A8 = second ? A18 : A08;
        const ushort* BT = second ? B1T : B0T;
        const int kb = (second ? (kt - 8) : kt) * 32;

        {   // 8 fp8 -> 8 bf16 (exact) -> 16B LDS write
            const uint2 q = *reinterpret_cast<const uint2*>(A8 + (size_t)agrow * 256 + kb + ach);
            const f32x2 f0 = __builtin_amdgcn_cvt_pk_f32_fp8(q.x, 0);
            const f32x2 f1 = __builtin_amdgcn_cvt_pk_f32_fp8(q.x, 1);
            const f32x2 f2 = __builtin_amdgcn_cvt_pk_f32_fp8(q.y, 0);
            const f32x2 f3 = __builtin_amdgcn_cvt_pk_f32_fp8(q.y, 1);
            uint4 o;
            o.x = cvt2bf(f0.x, f0.y);
            o.y = cvt2bf(f1.x, f1.y);
            o.z = cvt2bf(f2.x, f2.y);
            o.w = cvt2bf(f3.x, f3.y);
            *reinterpret_cast<uint4*>(&As[arr][ach]) = o;
        }
        #pragma unroll
        for (int it = 0; it < 2; ++it) {
            const int idx = it * 512 + tid;
            const int br = idx >> 2;
            const int ch = (idx & 3) * 8;
            *reinterpret_cast<float4*>(&Bs[br][ch]) =
                *reinterpret_cast<const float4*>(BT + (size_t)br * 256 + kb + ch);
        }
        __syncthreads();

        bf16x8 af[4], bfr[4];
        #pragma unroll
        for (int i = 0; i < 4; ++i)
            af[i] = *reinterpret_cast<const bf16x8*>(&As[wm * 64 + 16 * i + l15][l4 * 8]);
        #pragma unroll
        for (int j = 0; j < 4; ++j)
            bfr[j] = *reinterpret_cast<const bf16x8*>(&Bs[wn * 64 + 16 * j + l15][l4 * 8]);
        #pragma unroll
        for (int i = 0; i < 4; ++i)
            #pragma unroll
            for (int j = 0; j < 4; ++j)
                acc[i][j] = __builtin_amdgcn_mfma_f32_16x16x32_bf16(af[i], bfr[j], acc[i][j], 0, 0, 0);
        __syncthreads();
    }

    const int rbase = r0 + wm * 64;
    const int cbase = wn * 64;
    #pragma unroll
    for (int i = 0; i < 4; ++i) {
        #pragma unroll
        for (int r = 0; r < 4; ++r) {
            const int row = rbase + 16 * i + l4 * 4 + r;
            if (row < N) {
                #pragma unroll
                for (int j = 0; j < 4; ++j) {
                    const int col = cbase + 16 * j + l15;
                    float v = fmaxf(acc[i][j][r] + bias[col], 0.f);  // relu always
                    if (OUTBF)
                        outb[(size_t)row * 256 + col] = f2b(v);
                    if (OUT8)
                        out8[(size_t)row * 256 + col] = f2fp8(v);
                }
            }
        }
    }
}

// ---------------- fused post-MP: t1 = A@W1+b1 ; out = logsoftmax(t1@W2+b2) ----------------
// 512 threads, 128 rows/block. t1 (128x256 bf16) lives in LDS between the two GEMMs.
__global__ __launch_bounds__(512) void mlp_kernel(
    const ushort* __restrict__ A0, const ushort* __restrict__ W1T,
    const ushort* __restrict__ W2T,
    const float* __restrict__ b1, const float* __restrict__ b2,
    float* __restrict__ out, int N)
{
    __shared__ ushort As[128][40];
    __shared__ ushort Bs[256][40];
    __shared__ ushort T[128][264];   // 264-ushort stride: 2-way bank alias (free)
    __shared__ float msh[2][128];
    __shared__ float ssh[2][128];

    const int tid = threadIdx.x;
    const int wave = tid >> 6;
    const int lane = tid & 63;
    const int l15 = lane & 15;
    const int l4 = lane >> 4;
    const int r0 = blockIdx.x * 128;

    const f32x4 zero = {0.f, 0.f, 0.f, 0.f};

    // ---- phase 1: t1 = A0 @ W1 + b1  (128 x 256) ----
    {
        const int wm = wave >> 2;
        const int wn = wave & 3;
        f32x4 acc[4][4];
        #pragma unroll
        for (int i = 0; i < 4; ++i)
            #pragma unroll
            for (int j = 0; j < 4; ++j) acc[i][j] = zero;

        const int arr = tid >> 2;
        const int ach = (tid & 3) * 8;
        const int agrow = min(r0 + arr, N - 1);

        for (int kt = 0; kt < 8; ++kt) {
            const int kb = kt * 32;
            *reinterpret_cast<float4*>(&As[arr][ach]) =
                *reinterpret_cast<const float4*>(A0 + (size_t)agrow * 256 + kb + ach);
            #pragma unroll
            for (int it = 0; it < 2; ++it) {
                const int idx = it * 512 + tid;
                const int br = idx >> 2;
                const int ch = (idx & 3) * 8;
                *reinterpret_cast<float4*>(&Bs[br][ch]) =
                    *reinterpret_cast<const float4*>(W1T + (size_t)br * 256 + kb + ch);
            }
            __syncthreads();

            bf16x8 af[4], bfr[4];
            #pragma unroll
            for (int i = 0; i < 4; ++i)
                af[i] = *reinterpret_cast<const bf16x8*>(&As[wm * 64 + 16 * i + l15][l4 * 8]);
            #pragma unroll
            for (int j = 0; j < 4; ++j)
                bfr[j] = *reinterpret_cast<const bf16x8*>(&Bs[wn * 64 + 16 * j + l15][l4 * 8]);
            #pragma unroll
            for (int i = 0; i < 4; ++i)
                #pragma unroll
                for (int j = 0; j < 4; ++j)
                    acc[i][j] = __builtin_amdgcn_mfma_f32_16x16x32_bf16(af[i], bfr[j], acc[i][j], 0, 0, 0);
            __syncthreads();
        }

        const int rbase = wm * 64;
        const int cbase = wn * 64;
        #pragma unroll
        for (int i = 0; i < 4; ++i) {
            #pragma unroll
            for (int r = 0; r < 4; ++r) {
                const int row = rbase + 16 * i + l4 * 4 + r;
                #pragma unroll
                for (int j = 0; j < 4; ++j) {
                    const int col = cbase + 16 * j + l15;
                    T[row][col] = f2b(acc[i][j][r] + b1[col]);
                }
            }
        }
    }
    __syncthreads();

    // ---- phase 2: t2 = t1 @ W2 + b2 (128 x 128), fused log-softmax ----
    {
        const int wm = wave >> 1;
        const int wn = wave & 1;
        f32x4 acc[2][4];
        #pragma unroll
        for (int i = 0; i < 2; ++i)
            #pragma unroll
            for (int j = 0; j < 4; ++j) acc[i][j] = zero;

        for (int kt = 0; kt < 8; ++kt) {
            const int kb = kt * 32;
            {
                const int br = tid >> 2;
                const int ch = (tid & 3) * 8;
                *reinterpret_cast<float4*>(&Bs[br][ch]) =
                    *reinterpret_cast<const float4*>(W2T + (size_t)br * 256 + kb + ch);
            }
            __syncthreads();

            bf16x8 af[2], bfr[4];
            #pragma unroll
            for (int i = 0; i < 2; ++i)
                af[i] = *reinterpret_cast<const bf16x8*>(&T[wm * 32 + 16 * i + l15][kb + l4 * 8]);
            #pragma unroll
            for (int j = 0; j < 4; ++j)
                bfr[j] = *reinterpret_cast<const bf16x8*>(&Bs[wn * 64 + 16 * j + l15][l4 * 8]);
            #pragma unroll
            for (int i = 0; i < 2; ++i)
                #pragma unroll
                for (int j = 0; j < 4; ++j)
                    acc[i][j] = __builtin_amdgcn_mfma_f32_16x16x32_bf16(af[i], bfr[j], acc[i][j], 0, 0, 0);
            __syncthreads();
        }

        const int cbase = wn * 64;
        float bb[4];
        #pragma unroll
        for (int j = 0; j < 4; ++j) bb[j] = b2[cbase + 16 * j + l15];

        #pragma unroll
        for (int i = 0; i < 2; ++i) {
            #pragma unroll
            for (int r = 0; r < 4; ++r) {
                float v0 = acc[i][0][r] + bb[0];
                float v1 = acc[i][1][r] + bb[1];
                float v2 = acc[i][2][r] + bb[2];
                float v3 = acc[i][3][r] + bb[3];
                float m = fmaxf(fmaxf(v0, v1), fmaxf(v2, v3));
                #pragma unroll
                for (int off = 8; off > 0; off >>= 1) m = fmaxf(m, __shfl_xor(m, off));
                float s = expf(v0 - m) + expf(v1 - m) + expf(v2 - m) + expf(v3 - m);
                #pragma unroll
                for (int off = 8; off > 0; off >>= 1) s += __shfl_xor(s, off);
                if (l15 == 0) {
                    const int lr = wm * 32 + 16 * i + l4 * 4 + r;
                    msh[wn][lr] = m;
                    ssh[wn][lr] = s;
                }
            }
        }
        __syncthreads();

        #pragma unroll
        for (int i = 0; i < 2; ++i) {
            #pragma unroll
            for (int r = 0; r < 4; ++r) {
                const int lr = wm * 32 + 16 * i + l4 * 4 + r;
                const float m0 = msh[0][lr], m1 = msh[1][lr];
                const float s0 = ssh[0][lr], s1 = ssh[1][lr];
                const float M = fmaxf(m0, m1);
                const float ls = M + logf(s0 * expf(m0 - M) + s1 * expf(m1 - M));
                const int row = r0 + lr;
                if (row < N) {
                    #pragma unroll
                    for (int j = 0; j < 4; ++j)
                        out[(size_t)row * DOUT + cbase + 16 * j + l15] = acc[i][j][r] + bb[j] - ls;
                }
            }
        }
    }
}

extern "C" void kernel_launch(void* const* d_in, const int* in_sizes, int n_in,
                              void* d_out, int out_size, void* d_ws, size_t ws_size,
                              hipStream_t stream) {
    const float* x  = (const float*)d_in[0];
    const int* ei   = (const int*)d_in[1];
    const float* wl = (const float*)d_in[2];
    const float* bl = (const float*)d_in[3];
    const float* wr = (const float*)d_in[4];
    const float* w1 = (const float*)d_in[5];
    const float* b1 = (const float*)d_in[6];
    const float* w2 = (const float*)d_in[7];
    const float* b2 = (const float*)d_in[8];
    const int* src = ei;
    const int* dst = ei + NE;

    // ---- workspace layout ----
    ushort* hA   = (ushort*)d_ws;                 // NN*D bf16 (layer-2 out -> mlp in)
    ushort* wlT  = hA + (size_t)NN * D;           // 3*256*256
    ushort* wrT  = wlT + 3 * 256 * 256;
    ushort* w1T  = wrT + 3 * 256 * 256;
    ushort* w2T  = w1T + 256 * 256;               // 128*256
    unsigned char* h8x = (unsigned char*)(w2T + 128 * 256);  // NN*D fp8
    unsigned char* h8A = h8x + (size_t)NN * D;
    unsigned char* h8B = h8A + (size_t)NN * D;
    unsigned char* agg8 = h8B + (size_t)NN * D;   // NN*D fp8
    float* invd  = (float*)(agg8 + (size_t)NN * D);  // NN
    int* row_ptr = (int*)(invd + NN);               // NN+1
    int* csr_src = row_ptr + NN + 1;                // NE
    unsigned* ebuf = (unsigned*)(csr_src + NE);     // NE
    int* gcnt    = (int*)(ebuf + NE);               // NSCAN
    int* roff    = gcnt + NSCAN;                    // NSCAN+1
    int* blk     = roff + NSCAN + 1;                // 256
    float* outf  = (float*)d_out;

    // ---- CSR build (counting sort, XCD-local writes) ----
    const int NSB = (NSCAN + 256) / 256;  // 77
    bcount_kernel<<<NBLK, 256, 0, stream>>>(dst, gcnt, NE);
    scanA_kernel<<<NSB, 256, 0, stream>>>(gcnt, blk, NSCAN);
    scanB_kernel<<<1, 256, 0, stream>>>(blk, NSB);
    scanC_kernel<<<NSB, 256, 0, stream>>>(gcnt, blk, roff, NSCAN);
    bscatter_kernel<<<NBLK, 256, 0, stream>>>(src, dst, roff, ebuf, NE);
    bcsr_kernel<<<NBUCK, 256, 0, stream>>>(ebuf, roff, csr_src, row_ptr, invd);

    // ---- converts ----
    cvt_x_kernel<<<(NN * D / 4 + 255) / 256, 256, 0, stream>>>(x, (unsigned*)h8x, NN * D / 4);
    cvt_w_kernel<<<1920, 256, 0, stream>>>(wl, wr, w1, w2, wlT, wrT, w1T, w2T);

    const int gpan = (NN + 127) / 128;
    const int gg = (NN + 3) / 4;

    // layer 0: gather(h8x)->agg8 ; DUAL(agg8, h8x) -> h8A (fp8 only)
    gather_kernel<<<gg, 256, 0, stream>>>(h8x, csr_src, row_ptr, invd, agg8, NN);
    mgemm256f8_kernel<false, true><<<gpan, 512, 0, stream>>>(
        agg8, h8x, wlT, wrT, bl, nullptr, h8A, NN);
    // layer 1: -> h8B (fp8 only)
    gather_kernel<<<gg, 256, 0, stream>>>(h8A, csr_src, row_ptr, invd, agg8, NN);
    mgemm256f8_kernel<false, true><<<gpan, 512, 0, stream>>>(
        agg8, h8A, wlT + 256 * 256, wrT + 256 * 256, bl + 256, nullptr, h8B, NN);
    // layer 2: -> hA (bf16 only, feeds mlp)
    gather_kernel<<<gg, 256, 0, stream>>>(h8B, csr_src, row_ptr, invd, agg8, NN);
    mgemm256f8_kernel<true, false><<<gpan, 512, 0, stream>>>(
        agg8, h8B, wlT + 2 * 256 * 256, wrT + 2 * 256 * 256, bl + 2 * 256, hA, nullptr, NN);
    // fused post-MP (mp1 + mp2 + log-softmax)
    mlp_kernel<<<gpan, 512, 0, stream>>>(hA, w1T, w2T, b1, b2, outf, NN);
}